// Round 2
// baseline (24232.614 us; speedup 1.0000x reference)
//
#include <hip/hip_runtime.h>
#include <hip/hip_bf16.h>

// DTGCN: B=16,N=256,T=64,W=12,H=64,ED=64,S=5,C=4,E=2048, FG=76
// Persistent cooperative kernel: 256 WGs x 256 thr; batch = blockIdx&15,
// wg = blockIdx>>4 (16 WGs per batch). 3 device-scope barriers per step.
// Inputs auto-detected fp32-vs-bf16 and converted once to fp32 in workspace.

typedef unsigned short u16;
typedef unsigned int u32;

#define B_ 16
#define N_ 256
#define T_ 64
#define W_ 12
#define S_ 5
#define E_ 2048
#define FG_ 76
#define G_ 16   // workgroups per batch

__device__ __forceinline__ float b2f(u16 u) {
  union { u32 i; float f; } v; v.i = ((u32)u) << 16; return v.f;
}
__device__ __forceinline__ u16 f2b(float f) {  // round-to-nearest-even
  union { float f; u32 i; } v; v.f = f;
  u32 x = v.i; x += 0x7fff + ((x >> 16) & 1); return (u16)(x >> 16);
}
__device__ __forceinline__ float ftanh(float x) {
  float e = __expf(-2.f * fabsf(x));
  float t = (1.f - e) / (1.f + e);
  return x < 0.f ? -t : t;
}
__device__ __forceinline__ float fsigm(float x) { return 1.f / (1.f + __expf(-x)); }
__device__ __forceinline__ float cvload(const void* p, int i, int f) {
  return f ? ((const float*)p)[i] : b2f(((const u16*)p)[i]);
}

struct Params {
  const void *x0, *ew0, *gw0, *gb0, *w10, *b10, *w20, *b20;
  const void *wzc0, *bzc0, *wzl0, *bzl0, *wrc0, *brc0, *wrl0, *brl0;
  const void *whc0, *bhc0, *whl0, *bhl0, *clsw0, *clsb0;
  const int* eidx;
  // fp32-converted copies in workspace
  float *xf, *ewf, *gwf, *gbf, *b1f, *b2ff;
  float *wzcf, *bzcf, *wzlf, *bzlf, *wrcf, *brcf, *wrlf, *brlf;
  float *whcf, *bhcf, *whlf, *bhlf, *clswf, *clsbf;
  u16 *w1h, *w2h;  // bf16 copies for LDS staging
  // state
  float *AnT, *dinvS, *uvF, *XW, *de1, *de2, *h, *Msum, *degsum, *Eh, *Ascr;
  int *bar, *flag;
  void* out;
};

// ---- per-batch barrier across G_ workgroups (device scope) ----
__device__ __forceinline__ void bbar(int* ctr, int& cnt) {
  ++cnt;
  __syncthreads();
  if (threadIdx.x == 0) {
    __threadfence();  // release all our global writes to device scope
    __hip_atomic_fetch_add(ctr, 1, __ATOMIC_RELEASE, __HIP_MEMORY_SCOPE_AGENT);
    const int target = cnt * G_;
    while (__hip_atomic_load(ctr, __ATOMIC_ACQUIRE, __HIP_MEMORY_SCOPE_AGENT) < target)
      __builtin_amdgcn_s_sleep(4);
    __threadfence();  // acquire: invalidate stale caches
  }
  __syncthreads();
}

// ================= dtype detect + convert =================
__global__ void k_detect(Params p) {
  if (threadIdx.x == 0) {
    const u16* q = (const u16*)p.x0;
    int c = 0;
    for (int i = 0; i < 256; ++i) {
      int ex = (q[i] >> 7) & 0xff;         // bf16 exponent field
      c += (ex >= 110 && ex <= 135);       // plausible for ~N(0,1) magnitudes
    }
    // bf16 data: ~256 pass. fp32 data read as u16 pairs: ~141 pass.
    *p.flag = (c < 200) ? 1 : 0;           // 1 = inputs are fp32
  }
}

__global__ void k_convert(Params p) {
  const int f = *p.flag;
  const int blk = blockIdx.x, tid = threadIdx.x;
  if (blk < 32) {  // x: 262144 elements
    const int base = blk * 8192;
    for (int i = tid; i < 8192; i += 256) p.xf[base + i] = cvload(p.x0, base + i, f);
    return;
  }
  if (blk == 51) { for (int i = tid; i < 4096; i += 256) p.w1h[i] = f ? f2b(((const float*)p.w10)[i]) : ((const u16*)p.w10)[i]; return; }
  if (blk == 52) { for (int i = tid; i < 4096; i += 256) p.w2h[i] = f ? f2b(((const float*)p.w20)[i]) : ((const u16*)p.w20)[i]; return; }
  const void* src = nullptr; float* dst = nullptr; int n = 0;
  switch (blk) {
    case 32: src = p.ew0;  dst = p.ewf;  n = E_;      break;
    case 33: src = p.gw0;  dst = p.gwf;  n = FG_ * 64; break;
    case 34: src = p.gb0;  dst = p.gbf;  n = 64;      break;
    case 35: src = p.b10;  dst = p.b1f;  n = 64;      break;
    case 36: src = p.b20;  dst = p.b2ff; n = 64;      break;
    case 37: src = p.wzc0; dst = p.wzcf; n = 64;      break;
    case 38: src = p.bzc0; dst = p.bzcf; n = 64;      break;
    case 39: src = p.wzl0; dst = p.wzlf; n = 8192;    break;
    case 40: src = p.bzl0; dst = p.bzlf; n = 64;      break;
    case 41: src = p.wrc0; dst = p.wrcf; n = 64;      break;
    case 42: src = p.brc0; dst = p.brcf; n = 64;      break;
    case 43: src = p.wrl0; dst = p.wrlf; n = 8192;    break;
    case 44: src = p.brl0; dst = p.brlf; n = 64;      break;
    case 45: src = p.whc0; dst = p.whcf; n = 64;      break;
    case 46: src = p.bhc0; dst = p.bhcf; n = 64;      break;
    case 47: src = p.whl0; dst = p.whlf; n = 8192;    break;
    case 48: src = p.bhl0; dst = p.bhlf; n = 64;      break;
    case 49: src = p.clsw0; dst = p.clswf; n = 65536; break;
    case 50: src = p.clsb0; dst = p.clsbf; n = 4;     break;
    default: return;
  }
  for (int i = tid; i < n; i += 256) dst[i] = cvload(src, i, f);
}

// ================= init kernels =================
__global__ void k_scatter(Params p) {
  for (int e = threadIdx.x; e < E_; e += 256) {
    int s = p.eidx[e], d = p.eidx[E_ + e];
    atomicAdd(&p.Ascr[s * N_ + d], p.ewf[e]);
  }
}
__global__ void k_deg(Params p) {
  int j = threadIdx.x;
  float dg = 1.f;
  for (int i = 0; i < N_; ++i) dg += p.Ascr[i * N_ + j];
  p.dinvS[j] = rsqrtf(dg);
}
__global__ void k_ant(Params p) {
  int i = blockIdx.x, j = threadIdx.x;
  float a = p.Ascr[i * N_ + j] + (i == j ? 1.f : 0.f);
  p.AnT[j * N_ + i] = p.dinvS[i] * a * p.dinvS[j];
}
__global__ void k_uv(Params p) {
  int e = threadIdx.x; if (e >= 64) return;
  float uz = 0, vz = 0, ur = 0, vr = 0, uh = 0, vh = 0;
  for (int f = 0; f < 64; ++f) {
    float wz = p.wzlf[f * 64 + e], wr = p.wrlf[f * 64 + e], wh = p.whlf[f * 64 + e];
    uz += p.wzcf[f] * wz; vz += p.bzcf[f] * wz;
    ur += p.wrcf[f] * wr; vr += p.brcf[f] * wr;
    uh += p.whcf[f] * wh; vh += p.bhcf[f] * wh;
  }
  p.uvF[0 * 64 + e] = uz; p.uvF[1 * 64 + e] = vz + p.bzlf[e];
  p.uvF[2 * 64 + e] = ur; p.uvF[3 * 64 + e] = vr + p.brlf[e];
  p.uvF[4 * 64 + e] = uh; p.uvF[5 * 64 + e] = vh + p.bhlf[e];
}

// ================= main persistent kernel =================
__global__ void __launch_bounds__(256) dtgcn_main(Params p) {
  __shared__ float s_gw[FG_ * 64];
  __shared__ u16 s_w1[64 * 64], s_w2[64 * 64];
  __shared__ float s_gb[64], s_b1[64], s_b2[64];
  __shared__ float s_uv[6 * 64];
  __shared__ float s_y[256], s_dinv[256], s_s[16];
  __shared__ __align__(16) float s_buf[4 * 16 * 68];
  __shared__ float s_col[256];

  const int b = blockIdx.x & 15;
  const int wg = blockIdx.x >> 4;
  const int tid = threadIdx.x;
  const int lane = tid & 63;
  const int wv = tid >> 6;
  const int r0 = wg * 16;

  for (int i = tid; i < FG_ * 64; i += 256) s_gw[i] = p.gwf[i];
  for (int i = tid; i < 64 * 64; i += 256) { s_w1[i] = p.w1h[i]; s_w2[i] = p.w2h[i]; }
  if (tid < 64) { s_gb[tid] = p.gbf[tid]; s_b1[tid] = p.b1f[tid]; s_b2[tid] = p.b2ff[tid]; }
  for (int i = tid; i < 6 * 64; i += 256) s_uv[i] = p.uvF[i];
  __syncthreads();

  float* XWb  = p.XW  + (size_t)b * N_ * 64;
  float* de1b = p.de1 + (size_t)b * N_ * 64;
  float* de2b = p.de2 + (size_t)b * N_ * 64;
  float* hb   = p.h   + (size_t)b * N_ * 64;
  float* Msb  = p.Msum + (size_t)b * N_ * N_;
  float* degb = p.degsum + (size_t)b * N_;
  int* bar = p.bar + b;
  int bcnt = 0;

  for (int t = 0; t < T_; ++t) {
    // ---------- phase 1: XW = [win | h] @ gw ----------
    {
      const int row = r0 + wv * 4;
      float acc[4], xr[4], hr[4];
      #pragma unroll
      for (int r = 0; r < 4; ++r) {
        const int i = row + r;
        const int tx = t - (W_ - 1) + lane;
        xr[r] = (lane < W_ && tx >= 0) ? p.xf[((size_t)b * N_ + i) * T_ + tx] : 0.f;
        hr[r] = hb[i * 64 + lane];
        acc[r] = 0.f;
      }
      for (int k = 0; k < W_; ++k) {
        float gv = s_gw[k * 64 + lane];
        #pragma unroll
        for (int r = 0; r < 4; ++r) acc[r] += __shfl(xr[r], k) * gv;
      }
      for (int m = 0; m < 64; ++m) {
        float gv = s_gw[(W_ + m) * 64 + lane];
        #pragma unroll
        for (int r = 0; r < 4; ++r) acc[r] += __shfl(hr[r], m) * gv;
      }
      #pragma unroll
      for (int r = 0; r < 4; ++r) XWb[(row + r) * 64 + lane] = acc[r];
    }
    bbar(bar, bcnt);  // B1

    // ---------- phase 2: df = AnT@XW + gb ; de1/de2 = tanh(df@w1/2 + b) ----------
    {
      const int jrow = r0 + wv * 4;
      float df[4];
      #pragma unroll
      for (int r = 0; r < 4; ++r) df[r] = s_gb[lane];
      for (int ch = 0; ch < 4; ++ch) {
        __syncthreads();
        for (int q = tid; q < 4096; q += 256) s_buf[q] = XWb[ch * 4096 + q];
        __syncthreads();
        float ar[4];
        #pragma unroll
        for (int r = 0; r < 4; ++r) ar[r] = p.AnT[(jrow + r) * N_ + ch * 64 + lane];
        for (int m = 0; m < 64; ++m) {
          float xwv = s_buf[m * 64 + lane];
          #pragma unroll
          for (int r = 0; r < 4; ++r) df[r] += __shfl(ar[r], m) * xwv;
        }
      }
      float e1[4], e2[4];
      #pragma unroll
      for (int r = 0; r < 4; ++r) { e1[r] = s_b1[lane]; e2[r] = s_b2[lane]; }
      for (int f = 0; f < 64; ++f) {
        float w1v = b2f(s_w1[f * 64 + lane]);
        float w2v = b2f(s_w2[f * 64 + lane]);
        #pragma unroll
        for (int r = 0; r < 4; ++r) {
          float dv = __shfl(df[r], f);
          e1[r] += dv * w1v; e2[r] += dv * w2v;
        }
      }
      #pragma unroll
      for (int r = 0; r < 4; ++r) {
        de1b[(jrow + r) * 64 + lane] = ftanh(e1[r]);
        de2b[(jrow + r) * 64 + lane] = ftanh(e2[r]);
      }
    }
    bbar(bar, bcnt);  // B2

    // ---------- phase 3: Et (triangle), Msum/Eh ring update, degsum delta ----------
    {
      const int sidx = t % S_;
      float* Ehb = p.Eh + (size_t)(b * S_ + sidx) * N_ * N_;
      s_col[tid] = 0.f;
      __syncthreads();
      for (int tile = wg; tile < 136; tile += G_) {
        int I = 0, rem = tile;
        while (rem >= 16 - I) { rem -= 16 - I; ++I; }
        const int J = I + rem;
        __syncthreads();
        float* T1I = s_buf;        float* T2J = s_buf + 1088;
        float* T1J = s_buf + 2176; float* T2I = s_buf + 3264;
        for (int q = tid; q < 1024; q += 256) {
          int rr = q >> 6, cc = q & 63;
          T1I[rr * 68 + cc] = de1b[(I * 16 + rr) * 64 + cc];
          T2J[rr * 68 + cc] = de2b[(J * 16 + rr) * 64 + cc];
          T1J[rr * 68 + cc] = de1b[(J * 16 + rr) * 64 + cc];
          T2I[rr * 68 + cc] = de2b[(I * 16 + rr) * 64 + cc];
        }
        __syncthreads();
        const int ti = tid >> 4, tj = tid & 15;
        const bool active = (I != J) || (ti < tj);
        float dcj = 0.f, dci = 0.f;
        if (active) {
          const float4* a1 = (const float4*)(T1I + ti * 68);
          const float4* b1 = (const float4*)(T2J + tj * 68);
          const float4* a2 = (const float4*)(T1J + tj * 68);
          const float4* b2 = (const float4*)(T2I + ti * 68);
          float d1 = 0.f, d2 = 0.f;
          #pragma unroll
          for (int q = 0; q < 16; ++q) {
            float4 av = a1[q], bv = b1[q];
            d1 += av.x * bv.x + av.y * bv.y + av.z * bv.z + av.w * bv.w;
            float4 cv = a2[q], dv = b2[q];
            d2 += cv.x * dv.x + cv.y * dv.y + cv.z * dv.z + cv.w * dv.w;
          }
          float d = ftanh(d1 - d2);
          float eij = fmaxf(d, 0.f), eji = fmaxf(-d, 0.f);
          const int gi = I * 16 + ti, gj = J * 16 + tj;
          const int o1 = gi * N_ + gj, o2 = gj * N_ + gi;
          float old1 = Ehb[o1], old2 = Ehb[o2];
          Msb[o1] += eij - old1;
          Msb[o2] += eji - old2;
          Ehb[o1] = eij; Ehb[o2] = eji;
          dcj = eij - old1; dci = eji - old2;
        }
        dcj += __shfl_xor(dcj, 16); dcj += __shfl_xor(dcj, 32);
        dci += __shfl_xor(dci, 1);  dci += __shfl_xor(dci, 2);
        dci += __shfl_xor(dci, 4);  dci += __shfl_xor(dci, 8);
        if ((lane >> 4) == 0) atomicAdd(&s_col[J * 16 + (lane & 15)], dcj);
        if ((lane & 15) == 0) atomicAdd(&s_col[I * 16 + (wv * 4 + (lane >> 4))], dci);
      }
      __syncthreads();
      atomicAdd(&degb[tid], s_col[tid]);
    }
    bbar(bar, bcnt);  // B3

    // ---------- phase 4: dinv/y, s = dinv*(Msum^T y /cnt + y), GRU ----------
    {
      const float cnt = (float)((t + 1 < S_) ? (t + 1) : S_);
      const float invc = 1.f / cnt;
      {
        float dg = 1.f + degb[tid] * invc;
        float di = rsqrtf(dg);
        float xv = p.xf[((size_t)b * N_ + tid) * T_ + t];
        s_dinv[tid] = di;
        s_y[tid] = di * xv;
      }
      __syncthreads();
      {
        const int jj = tid & 15, c = tid >> 4;
        const int j = r0 + jj;
        float part = 0.f;
        for (int k = 0; k < 16; ++k) {
          int i2 = c * 16 + k;
          part += Msb[i2 * N_ + j] * s_y[i2];
        }
        s_buf[c * 16 + jj] = part;
      }
      __syncthreads();
      if (tid < 16) {
        float tot = 0.f;
        for (int k = 0; k < 16; ++k) tot += s_buf[k * 16 + tid];
        const int j = r0 + tid;
        s_s[tid] = s_dinv[j] * (tot * invc + s_y[j]);
      }
      __syncthreads();
      const int jrow = r0 + wv * 4;
      float hreg[4], sv[4], zz[4], rr2[4];
      #pragma unroll
      for (int r = 0; r < 4; ++r) {
        hreg[r] = hb[(jrow + r) * 64 + lane];
        sv[r] = s_s[wv * 4 + r];
      }
      // z gate
      __syncthreads();
      for (int q = tid; q < 4096; q += 256) s_buf[q] = p.wzlf[4096 + q];
      __syncthreads();
      {
        float a[4];
        #pragma unroll
        for (int r = 0; r < 4; ++r) a[r] = s_uv[0 * 64 + lane] * sv[r] + s_uv[1 * 64 + lane];
        for (int f = 0; f < 64; ++f) {
          float wt = s_buf[f * 64 + lane];
          #pragma unroll
          for (int r = 0; r < 4; ++r) a[r] += __shfl(hreg[r], f) * wt;
        }
        #pragma unroll
        for (int r = 0; r < 4; ++r) zz[r] = fsigm(a[r]);
      }
      // r gate
      __syncthreads();
      for (int q = tid; q < 4096; q += 256) s_buf[q] = p.wrlf[4096 + q];
      __syncthreads();
      {
        float a[4];
        #pragma unroll
        for (int r = 0; r < 4; ++r) a[r] = s_uv[2 * 64 + lane] * sv[r] + s_uv[3 * 64 + lane];
        for (int f = 0; f < 64; ++f) {
          float wt = s_buf[f * 64 + lane];
          #pragma unroll
          for (int r = 0; r < 4; ++r) a[r] += __shfl(hreg[r], f) * wt;
        }
        #pragma unroll
        for (int r = 0; r < 4; ++r) rr2[r] = fsigm(a[r]);
      }
      // candidate + update
      __syncthreads();
      for (int q = tid; q < 4096; q += 256) s_buf[q] = p.whlf[4096 + q];
      __syncthreads();
      {
        float hrg[4], a[4];
        #pragma unroll
        for (int r = 0; r < 4; ++r) {
          hrg[r] = hreg[r] * rr2[r];
          a[r] = s_uv[4 * 64 + lane] * sv[r] + s_uv[5 * 64 + lane];
        }
        for (int f = 0; f < 64; ++f) {
          float wt = s_buf[f * 64 + lane];
          #pragma unroll
          for (int r = 0; r < 4; ++r) a[r] += __shfl(hrg[r], f) * wt;
        }
        #pragma unroll
        for (int r = 0; r < 4; ++r) {
          float ht = ftanh(a[r]);
          float hn = zz[r] * hreg[r] + (1.f - zz[r]) * ht;
          hb[(jrow + r) * 64 + lane] = hn;
        }
      }
    }
  }
}

// ================= classifier =================
__global__ void k_cls(Params p) {
  __shared__ float red[256][4];
  const int b = blockIdx.x, i = threadIdx.x;
  const float* hr = p.h + ((size_t)b * N_ + i) * 64;
  const float* w = p.clswf + (size_t)i * 64 * 4;
  float a0 = 0, a1 = 0, a2 = 0, a3 = 0;
  for (int f = 0; f < 64; ++f) {
    float hv = hr[f];
    a0 += hv * w[f * 4 + 0]; a1 += hv * w[f * 4 + 1];
    a2 += hv * w[f * 4 + 2]; a3 += hv * w[f * 4 + 3];
  }
  red[i][0] = a0; red[i][1] = a1; red[i][2] = a2; red[i][3] = a3;
  __syncthreads();
  for (int st = 128; st > 0; st >>= 1) {
    if (i < st) {
      red[i][0] += red[i + st][0]; red[i][1] += red[i + st][1];
      red[i][2] += red[i + st][2]; red[i][3] += red[i + st][3];
    }
    __syncthreads();
  }
  if (i < 4) {
    float v = red[0][i] + p.clsbf[i];
    if (*p.flag) ((float*)p.out)[b * 4 + i] = v;
    else         ((u16*)p.out)[b * 4 + i] = f2b(v);
  }
}

extern "C" void kernel_launch(void* const* d_in, const int* in_sizes, int n_in,
                              void* d_out, int out_size, void* d_ws, size_t ws_size,
                              hipStream_t stream) {
  float* w = (float*)d_ws;
  size_t o = 0;
  auto alloc = [&](size_t n) { float* r = w + o; o += (n + 63) & ~(size_t)63; return r; };
  // converted inputs
  float* xf    = alloc(262144);
  float* ewf   = alloc(E_);
  float* gwf   = alloc(FG_ * 64);
  float* gbf   = alloc(64);
  float* b1f   = alloc(64);
  float* b2ff  = alloc(64);
  float* wzcf  = alloc(64); float* bzcf = alloc(64); float* wzlf = alloc(8192); float* bzlf = alloc(64);
  float* wrcf  = alloc(64); float* brcf = alloc(64); float* wrlf = alloc(8192); float* brlf = alloc(64);
  float* whcf  = alloc(64); float* bhcf = alloc(64); float* whlf = alloc(8192); float* bhlf = alloc(64);
  float* clswf = alloc(65536); float* clsbf = alloc(64);
  u16* w1h = (u16*)alloc(2048);
  u16* w2h = (u16*)alloc(2048);
  int* flag = (int*)alloc(64);
  // persistent state
  float* AnT   = alloc(65536);
  float* dinvS = alloc(256);
  float* uvF   = alloc(384);
  float* XW    = alloc((size_t)B_ * N_ * 64);
  float* de1   = alloc((size_t)B_ * N_ * 64);
  float* de2   = alloc((size_t)B_ * N_ * 64);
  const size_t zero_off = o;
  float* Ascr  = alloc((size_t)N_ * N_);
  float* h     = alloc((size_t)B_ * N_ * 64);
  float* Msum  = alloc((size_t)B_ * N_ * N_);
  float* degs  = alloc((size_t)B_ * N_);
  int*   bar   = (int*)alloc(64);
  float* Eh    = alloc((size_t)B_ * S_ * N_ * N_);
  if (ws_size < o * sizeof(float)) return;

  hipMemsetAsync(w + zero_off, 0, (o - zero_off) * sizeof(float), stream);

  Params p;
  p.x0  = d_in[0];  p.ew0 = d_in[1];
  p.gw0 = d_in[2];  p.gb0 = d_in[3];
  p.w10 = d_in[4];  p.b10 = d_in[5];
  p.w20 = d_in[6];  p.b20 = d_in[7];
  p.wzc0 = d_in[8];  p.bzc0 = d_in[9];  p.wzl0 = d_in[10]; p.bzl0 = d_in[11];
  p.wrc0 = d_in[12]; p.brc0 = d_in[13]; p.wrl0 = d_in[14]; p.brl0 = d_in[15];
  p.whc0 = d_in[16]; p.bhc0 = d_in[17]; p.whl0 = d_in[18]; p.bhl0 = d_in[19];
  p.clsw0 = d_in[20]; p.clsb0 = d_in[21];
  p.eidx = (const int*)d_in[22];
  p.xf = xf; p.ewf = ewf; p.gwf = gwf; p.gbf = gbf; p.b1f = b1f; p.b2ff = b2ff;
  p.wzcf = wzcf; p.bzcf = bzcf; p.wzlf = wzlf; p.bzlf = bzlf;
  p.wrcf = wrcf; p.brcf = brcf; p.wrlf = wrlf; p.brlf = brlf;
  p.whcf = whcf; p.bhcf = bhcf; p.whlf = whlf; p.bhlf = bhlf;
  p.clswf = clswf; p.clsbf = clsbf; p.w1h = w1h; p.w2h = w2h;
  p.AnT = AnT; p.dinvS = dinvS; p.uvF = uvF; p.XW = XW; p.de1 = de1; p.de2 = de2;
  p.h = h; p.Msum = Msum; p.degsum = degs; p.Eh = Eh; p.Ascr = Ascr;
  p.bar = bar; p.flag = flag; p.out = d_out;

  k_detect<<<1, 64, 0, stream>>>(p);
  k_convert<<<53, 256, 0, stream>>>(p);
  k_scatter<<<1, 256, 0, stream>>>(p);
  k_deg<<<1, 256, 0, stream>>>(p);
  k_ant<<<N_, 256, 0, stream>>>(p);
  k_uv<<<1, 64, 0, stream>>>(p);

  void* args[] = { &p };
  hipError_t ce = hipLaunchCooperativeKernel((const void*)dtgcn_main,
                                             dim3(B_ * G_), dim3(256), args, 0, stream);
  if (ce != hipSuccess) {
    (void)hipGetLastError();
    dtgcn_main<<<dim3(B_ * G_), dim3(256), 0, stream>>>(p);
  }

  k_cls<<<B_, 256, 0, stream>>>(p);
}

// Round 3
// 16994.002 us; speedup vs baseline: 1.4260x; 1.4260x over previous
//
#include <hip/hip_runtime.h>
#include <hip/hip_bf16.h>

// DTGCN: B=16,N=256,T=64,W=12,H=64,ED=64,S=5,C=4,E=2048, FG=76
// Persistent cooperative kernel: 256 WGs x 256 thr; batch = blockIdx&15,
// wg = blockIdx>>4 (16 WGs per batch). 3 fence-free barriers per step:
// all cross-WG data goes through sc0sc1 coherence-point loads/stores
// (relaxed SYSTEM-scope atomics), so barriers need no cache maintenance.

typedef unsigned short u16;
typedef unsigned int u32;

#define B_ 16
#define N_ 256
#define T_ 64
#define W_ 12
#define S_ 5
#define E_ 2048
#define FG_ 76
#define G_ 16   // workgroups per batch

__device__ __forceinline__ float b2f(u16 u) {
  union { u32 i; float f; } v; v.i = ((u32)u) << 16; return v.f;
}
__device__ __forceinline__ u16 f2b(float f) {  // round-to-nearest-even
  union { float f; u32 i; } v; v.f = f;
  u32 x = v.i; x += 0x7fff + ((x >> 16) & 1); return (u16)(x >> 16);
}
__device__ __forceinline__ float ftanh(float x) {
  float e = __expf(-2.f * fabsf(x));
  float t = (1.f - e) / (1.f + e);
  return x < 0.f ? -t : t;
}
__device__ __forceinline__ float fsigm(float x) { return 1.f / (1.f + __expf(-x)); }
__device__ __forceinline__ float cvload(const void* p, int i, int f) {
  return f ? ((const float*)p)[i] : b2f(((const u16*)p)[i]);
}
// coherence-point (sc0 sc1) accessors for cross-WG data — no fences needed
__device__ __forceinline__ float gld(const float* p) {
  return __hip_atomic_load(p, __ATOMIC_RELAXED, __HIP_MEMORY_SCOPE_SYSTEM);
}
__device__ __forceinline__ void gst(float* p, float v) {
  __hip_atomic_store(p, v, __ATOMIC_RELAXED, __HIP_MEMORY_SCOPE_SYSTEM);
}

struct Params {
  const void *x0, *ew0, *gw0, *gb0, *w10, *b10, *w20, *b20;
  const void *wzc0, *bzc0, *wzl0, *bzl0, *wrc0, *brc0, *wrl0, *brl0;
  const void *whc0, *bhc0, *whl0, *bhl0, *clsw0, *clsb0;
  const int* eidx;
  float *xf, *ewf, *gwf, *gbf, *b1f, *b2ff;
  float *wzcf, *bzcf, *wzlf, *bzlf, *wrcf, *brcf, *wrlf, *brlf;
  float *whcf, *bhcf, *whlf, *bhlf, *clswf, *clsbf;
  u16 *w1h, *w2h;
  float *AnT, *dinvS, *uvF, *XW, *de1, *de2, *h, *Msum, *degsum, *Eh, *Ascr;
  int *bar, *flag;
  void* out;
};

// ---- per-batch fence-free barrier across G_ workgroups ----
// __syncthreads drains vmcnt(0) for every wave => all prior sc0sc1 stores
// are acked at the coherence point before the counter bump is issued.
__device__ __forceinline__ void bbar(int* ctr, int& cnt) {
  ++cnt;
  __syncthreads();
  if (threadIdx.x == 0) {
    __hip_atomic_fetch_add(ctr, 1, __ATOMIC_RELAXED, __HIP_MEMORY_SCOPE_SYSTEM);
    const int target = cnt * G_;
    while (__hip_atomic_load(ctr, __ATOMIC_RELAXED, __HIP_MEMORY_SCOPE_SYSTEM) < target)
      __builtin_amdgcn_s_sleep(1);
  }
  __syncthreads();
}

// ================= dtype detect + convert =================
__global__ void k_detect(Params p) {
  if (threadIdx.x == 0) {
    const u16* q = (const u16*)p.x0;
    int c = 0;
    for (int i = 0; i < 256; ++i) {
      int ex = (q[i] >> 7) & 0xff;
      c += (ex >= 110 && ex <= 135);
    }
    *p.flag = (c < 200) ? 1 : 0;  // 1 = inputs are fp32
  }
}

__global__ void k_convert(Params p) {
  const int f = *p.flag;
  const int blk = blockIdx.x, tid = threadIdx.x;
  if (blk < 32) {
    const int base = blk * 8192;
    for (int i = tid; i < 8192; i += 256) p.xf[base + i] = cvload(p.x0, base + i, f);
    return;
  }
  if (blk == 51) { for (int i = tid; i < 4096; i += 256) p.w1h[i] = f ? f2b(((const float*)p.w10)[i]) : ((const u16*)p.w10)[i]; return; }
  if (blk == 52) { for (int i = tid; i < 4096; i += 256) p.w2h[i] = f ? f2b(((const float*)p.w20)[i]) : ((const u16*)p.w20)[i]; return; }
  const void* src = nullptr; float* dst = nullptr; int n = 0;
  switch (blk) {
    case 32: src = p.ew0;  dst = p.ewf;  n = E_;      break;
    case 33: src = p.gw0;  dst = p.gwf;  n = FG_ * 64; break;
    case 34: src = p.gb0;  dst = p.gbf;  n = 64;      break;
    case 35: src = p.b10;  dst = p.b1f;  n = 64;      break;
    case 36: src = p.b20;  dst = p.b2ff; n = 64;      break;
    case 37: src = p.wzc0; dst = p.wzcf; n = 64;      break;
    case 38: src = p.bzc0; dst = p.bzcf; n = 64;      break;
    case 39: src = p.wzl0; dst = p.wzlf; n = 8192;    break;
    case 40: src = p.bzl0; dst = p.bzlf; n = 64;      break;
    case 41: src = p.wrc0; dst = p.wrcf; n = 64;      break;
    case 42: src = p.brc0; dst = p.brcf; n = 64;      break;
    case 43: src = p.wrl0; dst = p.wrlf; n = 8192;    break;
    case 44: src = p.brl0; dst = p.brlf; n = 64;      break;
    case 45: src = p.whc0; dst = p.whcf; n = 64;      break;
    case 46: src = p.bhc0; dst = p.bhcf; n = 64;      break;
    case 47: src = p.whl0; dst = p.whlf; n = 8192;    break;
    case 48: src = p.bhl0; dst = p.bhlf; n = 64;      break;
    case 49: src = p.clsw0; dst = p.clswf; n = 65536; break;
    case 50: src = p.clsb0; dst = p.clsbf; n = 4;     break;
    default: return;
  }
  for (int i = tid; i < n; i += 256) dst[i] = cvload(src, i, f);
}

// ================= init kernels =================
__global__ void k_scatter(Params p) {
  for (int e = threadIdx.x; e < E_; e += 256) {
    int s = p.eidx[e], d = p.eidx[E_ + e];
    atomicAdd(&p.Ascr[s * N_ + d], p.ewf[e]);
  }
}
__global__ void k_deg(Params p) {
  int j = threadIdx.x;
  float dg = 1.f;
  for (int i = 0; i < N_; ++i) dg += p.Ascr[i * N_ + j];
  p.dinvS[j] = rsqrtf(dg);
}
__global__ void k_ant(Params p) {
  int i = blockIdx.x, j = threadIdx.x;
  float a = p.Ascr[i * N_ + j] + (i == j ? 1.f : 0.f);
  p.AnT[j * N_ + i] = p.dinvS[i] * a * p.dinvS[j];
}
__global__ void k_uv(Params p) {
  int e = threadIdx.x; if (e >= 64) return;
  float uz = 0, vz = 0, ur = 0, vr = 0, uh = 0, vh = 0;
  for (int f = 0; f < 64; ++f) {
    float wz = p.wzlf[f * 64 + e], wr = p.wrlf[f * 64 + e], wh = p.whlf[f * 64 + e];
    uz += p.wzcf[f] * wz; vz += p.bzcf[f] * wz;
    ur += p.wrcf[f] * wr; vr += p.brcf[f] * wr;
    uh += p.whcf[f] * wh; vh += p.bhcf[f] * wh;
  }
  p.uvF[0 * 64 + e] = uz; p.uvF[1 * 64 + e] = vz + p.bzlf[e];
  p.uvF[2 * 64 + e] = ur; p.uvF[3 * 64 + e] = vr + p.brlf[e];
  p.uvF[4 * 64 + e] = uh; p.uvF[5 * 64 + e] = vh + p.bhlf[e];
}

// ================= main persistent kernel =================
__global__ void __launch_bounds__(256) dtgcn_main(Params p) {
  __shared__ float s_gw[FG_ * 64];
  __shared__ u16 s_w1[64 * 64], s_w2[64 * 64];
  __shared__ float s_gb[64], s_b1[64], s_b2[64];
  __shared__ float s_uv[6 * 64];
  __shared__ float s_y[256], s_dinv[256], s_s[16];
  __shared__ __align__(16) float s_buf[4 * 16 * 68];
  __shared__ float s_col[256];

  const int b = blockIdx.x & 15;
  const int wg = blockIdx.x >> 4;
  const int tid = threadIdx.x;
  const int lane = tid & 63;
  const int wv = tid >> 6;
  const int r0 = wg * 16;

  for (int i = tid; i < FG_ * 64; i += 256) s_gw[i] = p.gwf[i];
  for (int i = tid; i < 64 * 64; i += 256) { s_w1[i] = p.w1h[i]; s_w2[i] = p.w2h[i]; }
  if (tid < 64) { s_gb[tid] = p.gbf[tid]; s_b1[tid] = p.b1f[tid]; s_b2[tid] = p.b2ff[tid]; }
  for (int i = tid; i < 6 * 64; i += 256) s_uv[i] = p.uvF[i];
  __syncthreads();

  float* XWb  = p.XW  + (size_t)b * N_ * 64;   // cross-WG: sc0sc1 only
  float* de1b = p.de1 + (size_t)b * N_ * 64;   // cross-WG: sc0sc1 only
  float* de2b = p.de2 + (size_t)b * N_ * 64;   // cross-WG: sc0sc1 only
  float* hb   = p.h   + (size_t)b * N_ * 64;   // WG-private: cached
  float* Msb  = p.Msum + (size_t)b * N_ * N_;  // cross-WG: sc0sc1 only
  float* degb = p.degsum + (size_t)b * N_;     // cross-WG: atomics/sc
  int* bar = p.bar + b;
  int bcnt = 0;

  for (int t = 0; t < T_; ++t) {
    // ---------- phase 1: XW = [win | h] @ gw ----------
    {
      const int row = r0 + wv * 4;
      float acc[4], xr[4], hr[4];
      #pragma unroll
      for (int r = 0; r < 4; ++r) {
        const int i = row + r;
        const int tx = t - (W_ - 1) + lane;
        xr[r] = (lane < W_ && tx >= 0) ? p.xf[((size_t)b * N_ + i) * T_ + tx] : 0.f;
        hr[r] = hb[i * 64 + lane];
        acc[r] = 0.f;
      }
      for (int k = 0; k < W_; ++k) {
        float gv = s_gw[k * 64 + lane];
        #pragma unroll
        for (int r = 0; r < 4; ++r) acc[r] += __shfl(xr[r], k) * gv;
      }
      for (int m = 0; m < 64; ++m) {
        float gv = s_gw[(W_ + m) * 64 + lane];
        #pragma unroll
        for (int r = 0; r < 4; ++r) acc[r] += __shfl(hr[r], m) * gv;
      }
      #pragma unroll
      for (int r = 0; r < 4; ++r) gst(&XWb[(row + r) * 64 + lane], acc[r]);
    }
    bbar(bar, bcnt);  // B1

    // ---------- phase 2: df = AnT@XW + gb ; de1/de2 = tanh(df@w1/2 + b) ----------
    {
      const int jrow = r0 + wv * 4;
      float df[4];
      #pragma unroll
      for (int r = 0; r < 4; ++r) df[r] = s_gb[lane];
      for (int ch = 0; ch < 4; ++ch) {
        __syncthreads();
        for (int q = tid; q < 4096; q += 256) s_buf[q] = gld(&XWb[ch * 4096 + q]);
        __syncthreads();
        float ar[4];
        #pragma unroll
        for (int r = 0; r < 4; ++r) ar[r] = p.AnT[(jrow + r) * N_ + ch * 64 + lane];
        for (int m = 0; m < 64; ++m) {
          float xwv = s_buf[m * 64 + lane];
          #pragma unroll
          for (int r = 0; r < 4; ++r) df[r] += __shfl(ar[r], m) * xwv;
        }
      }
      float e1[4], e2[4];
      #pragma unroll
      for (int r = 0; r < 4; ++r) { e1[r] = s_b1[lane]; e2[r] = s_b2[lane]; }
      for (int f = 0; f < 64; ++f) {
        float w1v = b2f(s_w1[f * 64 + lane]);
        float w2v = b2f(s_w2[f * 64 + lane]);
        #pragma unroll
        for (int r = 0; r < 4; ++r) {
          float dv = __shfl(df[r], f);
          e1[r] += dv * w1v; e2[r] += dv * w2v;
        }
      }
      #pragma unroll
      for (int r = 0; r < 4; ++r) {
        gst(&de1b[(jrow + r) * 64 + lane], ftanh(e1[r]));
        gst(&de2b[(jrow + r) * 64 + lane], ftanh(e2[r]));
      }
    }
    bbar(bar, bcnt);  // B2

    // ---------- phase 3: Et (triangle), Msum/Eh ring update, degsum delta ----------
    {
      const int sidx = t % S_;
      float* Ehb = p.Eh + (size_t)(b * S_ + sidx) * N_ * N_;  // WG/thread-private: cached
      s_col[tid] = 0.f;
      __syncthreads();
      for (int tile = wg; tile < 136; tile += G_) {
        int I = 0, rem = tile;
        while (rem >= 16 - I) { rem -= 16 - I; ++I; }
        const int J = I + rem;
        __syncthreads();
        float* T1I = s_buf;        float* T2J = s_buf + 1088;
        float* T1J = s_buf + 2176; float* T2I = s_buf + 3264;
        for (int q = tid; q < 1024; q += 256) {
          int rr = q >> 6, cc = q & 63;
          T1I[rr * 68 + cc] = gld(&de1b[(I * 16 + rr) * 64 + cc]);
          T2J[rr * 68 + cc] = gld(&de2b[(J * 16 + rr) * 64 + cc]);
          T1J[rr * 68 + cc] = gld(&de1b[(J * 16 + rr) * 64 + cc]);
          T2I[rr * 68 + cc] = gld(&de2b[(I * 16 + rr) * 64 + cc]);
        }
        __syncthreads();
        const int ti = tid >> 4, tj = tid & 15;
        const bool active = (I != J) || (ti < tj);
        float dcj = 0.f, dci = 0.f;
        if (active) {
          const float4* a1 = (const float4*)(T1I + ti * 68);
          const float4* b1 = (const float4*)(T2J + tj * 68);
          const float4* a2 = (const float4*)(T1J + tj * 68);
          const float4* b2 = (const float4*)(T2I + ti * 68);
          float d1 = 0.f, d2 = 0.f;
          #pragma unroll
          for (int q = 0; q < 16; ++q) {
            float4 av = a1[q], bv = b1[q];
            d1 += av.x * bv.x + av.y * bv.y + av.z * bv.z + av.w * bv.w;
            float4 cv = a2[q], dv = b2[q];
            d2 += cv.x * dv.x + cv.y * dv.y + cv.z * dv.z + cv.w * dv.w;
          }
          float d = ftanh(d1 - d2);
          float eij = fmaxf(d, 0.f), eji = fmaxf(-d, 0.f);
          const int gi = I * 16 + ti, gj = J * 16 + tj;
          const int o1 = gi * N_ + gj, o2 = gj * N_ + gi;
          float old1 = Ehb[o1], old2 = Ehb[o2];
          float m1 = gld(&Msb[o1]), m2 = gld(&Msb[o2]);
          gst(&Msb[o1], m1 + eij - old1);
          gst(&Msb[o2], m2 + eji - old2);
          Ehb[o1] = eij; Ehb[o2] = eji;
          dcj = eij - old1; dci = eji - old2;
        }
        dcj += __shfl_xor(dcj, 16); dcj += __shfl_xor(dcj, 32);
        dci += __shfl_xor(dci, 1);  dci += __shfl_xor(dci, 2);
        dci += __shfl_xor(dci, 4);  dci += __shfl_xor(dci, 8);
        if ((lane >> 4) == 0) atomicAdd(&s_col[J * 16 + (lane & 15)], dcj);
        if ((lane & 15) == 0) atomicAdd(&s_col[I * 16 + (wv * 4 + (lane >> 4))], dci);
      }
      __syncthreads();
      atomicAdd(&degb[tid], s_col[tid]);  // device-scope atomic: coherent
    }
    bbar(bar, bcnt);  // B3

    // ---------- phase 4: dinv/y, s = dinv*(Msum^T y /cnt + y), GRU ----------
    {
      const float cnt = (float)((t + 1 < S_) ? (t + 1) : S_);
      const float invc = 1.f / cnt;
      {
        float dg = 1.f + gld(&degb[tid]) * invc;
        float di = rsqrtf(dg);
        float xv = p.xf[((size_t)b * N_ + tid) * T_ + t];
        s_dinv[tid] = di;
        s_y[tid] = di * xv;
      }
      __syncthreads();
      {
        const int jj = tid & 15, c = tid >> 4;
        const int j = r0 + jj;
        float part = 0.f;
        for (int k = 0; k < 16; ++k) {
          int i2 = c * 16 + k;
          part += gld(&Msb[i2 * N_ + j]) * s_y[i2];
        }
        s_buf[c * 16 + jj] = part;
      }
      __syncthreads();
      if (tid < 16) {
        float tot = 0.f;
        for (int k = 0; k < 16; ++k) tot += s_buf[k * 16 + tid];
        const int j = r0 + tid;
        s_s[tid] = s_dinv[j] * (tot * invc + s_y[j]);
      }
      __syncthreads();
      const int jrow = r0 + wv * 4;
      float hreg[4], sv[4], zz[4], rr2[4];
      #pragma unroll
      for (int r = 0; r < 4; ++r) {
        hreg[r] = hb[(jrow + r) * 64 + lane];
        sv[r] = s_s[wv * 4 + r];
      }
      // z gate
      __syncthreads();
      for (int q = tid; q < 4096; q += 256) s_buf[q] = p.wzlf[4096 + q];
      __syncthreads();
      {
        float a[4];
        #pragma unroll
        for (int r = 0; r < 4; ++r) a[r] = s_uv[0 * 64 + lane] * sv[r] + s_uv[1 * 64 + lane];
        for (int f = 0; f < 64; ++f) {
          float wt = s_buf[f * 64 + lane];
          #pragma unroll
          for (int r = 0; r < 4; ++r) a[r] += __shfl(hreg[r], f) * wt;
        }
        #pragma unroll
        for (int r = 0; r < 4; ++r) zz[r] = fsigm(a[r]);
      }
      // r gate
      __syncthreads();
      for (int q = tid; q < 4096; q += 256) s_buf[q] = p.wrlf[4096 + q];
      __syncthreads();
      {
        float a[4];
        #pragma unroll
        for (int r = 0; r < 4; ++r) a[r] = s_uv[2 * 64 + lane] * sv[r] + s_uv[3 * 64 + lane];
        for (int f = 0; f < 64; ++f) {
          float wt = s_buf[f * 64 + lane];
          #pragma unroll
          for (int r = 0; r < 4; ++r) a[r] += __shfl(hreg[r], f) * wt;
        }
        #pragma unroll
        for (int r = 0; r < 4; ++r) rr2[r] = fsigm(a[r]);
      }
      // candidate + update
      __syncthreads();
      for (int q = tid; q < 4096; q += 256) s_buf[q] = p.whlf[4096 + q];
      __syncthreads();
      {
        float hrg[4], a[4];
        #pragma unroll
        for (int r = 0; r < 4; ++r) {
          hrg[r] = hreg[r] * rr2[r];
          a[r] = s_uv[4 * 64 + lane] * sv[r] + s_uv[5 * 64 + lane];
        }
        for (int f = 0; f < 64; ++f) {
          float wt = s_buf[f * 64 + lane];
          #pragma unroll
          for (int r = 0; r < 4; ++r) a[r] += __shfl(hrg[r], f) * wt;
        }
        #pragma unroll
        for (int r = 0; r < 4; ++r) {
          float ht = ftanh(a[r]);
          float hn = zz[r] * hreg[r] + (1.f - zz[r]) * ht;
          hb[(jrow + r) * 64 + lane] = hn;
        }
      }
    }
  }
}

// ================= classifier =================
__global__ void k_cls(Params p) {
  __shared__ float red[256][4];
  const int b = blockIdx.x, i = threadIdx.x;
  const float* hr = p.h + ((size_t)b * N_ + i) * 64;
  const float* w = p.clswf + (size_t)i * 64 * 4;
  float a0 = 0, a1 = 0, a2 = 0, a3 = 0;
  for (int f = 0; f < 64; ++f) {
    float hv = hr[f];
    a0 += hv * w[f * 4 + 0]; a1 += hv * w[f * 4 + 1];
    a2 += hv * w[f * 4 + 2]; a3 += hv * w[f * 4 + 3];
  }
  red[i][0] = a0; red[i][1] = a1; red[i][2] = a2; red[i][3] = a3;
  __syncthreads();
  for (int st = 128; st > 0; st >>= 1) {
    if (i < st) {
      red[i][0] += red[i + st][0]; red[i][1] += red[i + st][1];
      red[i][2] += red[i + st][2]; red[i][3] += red[i + st][3];
    }
    __syncthreads();
  }
  if (i < 4) {
    float v = red[0][i] + p.clsbf[i];
    if (*p.flag) ((float*)p.out)[b * 4 + i] = v;
    else         ((u16*)p.out)[b * 4 + i] = f2b(v);
  }
}

extern "C" void kernel_launch(void* const* d_in, const int* in_sizes, int n_in,
                              void* d_out, int out_size, void* d_ws, size_t ws_size,
                              hipStream_t stream) {
  float* w = (float*)d_ws;
  size_t o = 0;
  auto alloc = [&](size_t n) { float* r = w + o; o += (n + 63) & ~(size_t)63; return r; };
  float* xf    = alloc(262144);
  float* ewf   = alloc(E_);
  float* gwf   = alloc(FG_ * 64);
  float* gbf   = alloc(64);
  float* b1f   = alloc(64);
  float* b2ff  = alloc(64);
  float* wzcf  = alloc(64); float* bzcf = alloc(64); float* wzlf = alloc(8192); float* bzlf = alloc(64);
  float* wrcf  = alloc(64); float* brcf = alloc(64); float* wrlf = alloc(8192); float* brlf = alloc(64);
  float* whcf  = alloc(64); float* bhcf = alloc(64); float* whlf = alloc(8192); float* bhlf = alloc(64);
  float* clswf = alloc(65536); float* clsbf = alloc(64);
  u16* w1h = (u16*)alloc(2048);
  u16* w2h = (u16*)alloc(2048);
  int* flag = (int*)alloc(64);
  float* AnT   = alloc(65536);
  float* dinvS = alloc(256);
  float* uvF   = alloc(384);
  float* XW    = alloc((size_t)B_ * N_ * 64);
  float* de1   = alloc((size_t)B_ * N_ * 64);
  float* de2   = alloc((size_t)B_ * N_ * 64);
  const size_t zero_off = o;
  float* Ascr  = alloc((size_t)N_ * N_);
  float* h     = alloc((size_t)B_ * N_ * 64);
  float* Msum  = alloc((size_t)B_ * N_ * N_);
  float* degs  = alloc((size_t)B_ * N_);
  int*   bar   = (int*)alloc(64);
  float* Eh    = alloc((size_t)B_ * S_ * N_ * N_);
  if (ws_size < o * sizeof(float)) return;

  hipMemsetAsync(w + zero_off, 0, (o - zero_off) * sizeof(float), stream);

  Params p;
  p.x0  = d_in[0];  p.ew0 = d_in[1];
  p.gw0 = d_in[2];  p.gb0 = d_in[3];
  p.w10 = d_in[4];  p.b10 = d_in[5];
  p.w20 = d_in[6];  p.b20 = d_in[7];
  p.wzc0 = d_in[8];  p.bzc0 = d_in[9];  p.wzl0 = d_in[10]; p.bzl0 = d_in[11];
  p.wrc0 = d_in[12]; p.brc0 = d_in[13]; p.wrl0 = d_in[14]; p.brl0 = d_in[15];
  p.whc0 = d_in[16]; p.bhc0 = d_in[17]; p.whl0 = d_in[18]; p.bhl0 = d_in[19];
  p.clsw0 = d_in[20]; p.clsb0 = d_in[21];
  p.eidx = (const int*)d_in[22];
  p.xf = xf; p.ewf = ewf; p.gwf = gwf; p.gbf = gbf; p.b1f = b1f; p.b2ff = b2ff;
  p.wzcf = wzcf; p.bzcf = bzcf; p.wzlf = wzlf; p.bzlf = bzlf;
  p.wrcf = wrcf; p.brcf = brcf; p.wrlf = wrlf; p.brlf = brlf;
  p.whcf = whcf; p.bhcf = bhcf; p.whlf = whlf; p.bhlf = bhlf;
  p.clswf = clswf; p.clsbf = clsbf; p.w1h = w1h; p.w2h = w2h;
  p.AnT = AnT; p.dinvS = dinvS; p.uvF = uvF; p.XW = XW; p.de1 = de1; p.de2 = de2;
  p.h = h; p.Msum = Msum; p.degsum = degs; p.Eh = Eh; p.Ascr = Ascr;
  p.bar = bar; p.flag = flag; p.out = d_out;

  k_detect<<<1, 64, 0, stream>>>(p);
  k_convert<<<53, 256, 0, stream>>>(p);
  k_scatter<<<1, 256, 0, stream>>>(p);
  k_deg<<<1, 256, 0, stream>>>(p);
  k_ant<<<N_, 256, 0, stream>>>(p);
  k_uv<<<1, 64, 0, stream>>>(p);

  void* args[] = { &p };
  hipError_t ce = hipLaunchCooperativeKernel((const void*)dtgcn_main,
                                             dim3(B_ * G_), dim3(256), args, 0, stream);
  if (ce != hipSuccess) {
    (void)hipGetLastError();
    dtgcn_main<<<dim3(B_ * G_), dim3(256), 0, stream>>>(p);
  }

  k_cls<<<B_, 256, 0, stream>>>(p);
}

// Round 5
// 4366.696 us; speedup vs baseline: 5.5494x; 3.8917x over previous
//
#include <hip/hip_runtime.h>
#include <hip/hip_bf16.h>

// DTGCN: B=16,N=256,T=64,W=12,H=64,ED=64,S=5,C=4,E=2048, FG=76
// Persistent cooperative kernel: 256 WGs x 256 thr; batch = blockIdx&15,
// wg = blockIdx>>4 (16 WGs per batch). 3 fence-free barriers per step:
// cross-WG data via sc0sc1 (relaxed SYSTEM-scope) loads/stores resolving at
// the coherence point; barriers are relaxed counter + backoff spin.
// R5: fix s_sleep constant-operand compile error (branch to constant sleeps).

typedef unsigned short u16;
typedef unsigned int u32;

#define B_ 16
#define N_ 256
#define T_ 64
#define W_ 12
#define S_ 5
#define E_ 2048
#define FG_ 76
#define G_ 16   // workgroups per batch

__device__ __forceinline__ float b2f(u16 u) {
  union { u32 i; float f; } v; v.i = ((u32)u) << 16; return v.f;
}
__device__ __forceinline__ u16 f2b(float f) {  // round-to-nearest-even
  union { float f; u32 i; } v; v.f = f;
  u32 x = v.i; x += 0x7fff + ((x >> 16) & 1); return (u16)(x >> 16);
}
__device__ __forceinline__ float ftanh(float x) {
  float e = __expf(-2.f * fabsf(x));
  float t = (1.f - e) / (1.f + e);
  return x < 0.f ? -t : t;
}
__device__ __forceinline__ float fsigm(float x) { return 1.f / (1.f + __expf(-x)); }
__device__ __forceinline__ float cvload(const void* p, int i, int f) {
  return f ? ((const float*)p)[i] : b2f(((const u16*)p)[i]);
}
// coherence-point (sc0 sc1) accessors for cross-WG data
__device__ __forceinline__ float gld(const float* p) {
  return __hip_atomic_load(p, __ATOMIC_RELAXED, __HIP_MEMORY_SCOPE_SYSTEM);
}
__device__ __forceinline__ void gst(float* p, float v) {
  __hip_atomic_store(p, v, __ATOMIC_RELAXED, __HIP_MEMORY_SCOPE_SYSTEM);
}

struct Params {
  const void *x0, *ew0, *gw0, *gb0, *w10, *b10, *w20, *b20;
  const void *wzc0, *bzc0, *wzl0, *bzl0, *wrc0, *brc0, *wrl0, *brl0;
  const void *whc0, *bhc0, *whl0, *bhl0, *clsw0, *clsb0;
  const int* eidx;
  float *xf, *ewf, *gwf, *gbf, *b1f, *b2ff;
  float *wzcf, *bzcf, *wzlf, *bzlf, *wrcf, *brcf, *wrlf, *brlf;
  float *whcf, *bhcf, *whlf, *bhlf, *clswf, *clsbf;
  u16 *w1h, *w2h;
  float *AnT, *dinvS, *uvF, *XW, *de1, *de2, *h, *Msum, *degsum, *Eh, *Ascr;
  int *bar, *flag;
  void* out;
};

// ---- per-batch fence-free barrier (padded counter, backoff spin) ----
__device__ __forceinline__ void bbar(int* ctr, int& cnt) {
  ++cnt;
  __syncthreads();   // drains vmcnt: all prior sc stores/atomics are at L3
  if (threadIdx.x == 0) {
    __hip_atomic_fetch_add(ctr, 1, __ATOMIC_RELAXED, __HIP_MEMORY_SCOPE_SYSTEM);
    const int target = cnt * G_;
    int spins = 0;
    while (__hip_atomic_load(ctr, __ATOMIC_RELAXED, __HIP_MEMORY_SCOPE_SYSTEM) < target) {
      if (spins < 8) __builtin_amdgcn_s_sleep(1);
      else           __builtin_amdgcn_s_sleep(32);
      ++spins;
    }
  }
  __syncthreads();
}

// ================= dtype detect + convert =================
__global__ void k_detect(Params p) {
  if (threadIdx.x == 0) {
    const u16* q = (const u16*)p.x0;
    int c = 0;
    for (int i = 0; i < 256; ++i) {
      int ex = (q[i] >> 7) & 0xff;
      c += (ex >= 110 && ex <= 135);
    }
    *p.flag = (c < 200) ? 1 : 0;  // 1 = inputs are fp32
  }
}

__global__ void k_convert(Params p) {
  const int f = *p.flag;
  const int blk = blockIdx.x, tid = threadIdx.x;
  if (blk < 32) {
    const int base = blk * 8192;
    for (int i = tid; i < 8192; i += 256) p.xf[base + i] = cvload(p.x0, base + i, f);
    return;
  }
  if (blk == 51) { for (int i = tid; i < 4096; i += 256) p.w1h[i] = f ? f2b(((const float*)p.w10)[i]) : ((const u16*)p.w10)[i]; return; }
  if (blk == 52) { for (int i = tid; i < 4096; i += 256) p.w2h[i] = f ? f2b(((const float*)p.w20)[i]) : ((const u16*)p.w20)[i]; return; }
  const void* src = nullptr; float* dst = nullptr; int n = 0;
  switch (blk) {
    case 32: src = p.ew0;  dst = p.ewf;  n = E_;      break;
    case 33: src = p.gw0;  dst = p.gwf;  n = FG_ * 64; break;
    case 34: src = p.gb0;  dst = p.gbf;  n = 64;      break;
    case 35: src = p.b10;  dst = p.b1f;  n = 64;      break;
    case 36: src = p.b20;  dst = p.b2ff; n = 64;      break;
    case 37: src = p.wzc0; dst = p.wzcf; n = 64;      break;
    case 38: src = p.bzc0; dst = p.bzcf; n = 64;      break;
    case 39: src = p.wzl0; dst = p.wzlf; n = 8192;    break;
    case 40: src = p.bzl0; dst = p.bzlf; n = 64;      break;
    case 41: src = p.wrc0; dst = p.wrcf; n = 64;      break;
    case 42: src = p.brc0; dst = p.brcf; n = 64;      break;
    case 43: src = p.wrl0; dst = p.wrlf; n = 8192;    break;
    case 44: src = p.brl0; dst = p.brlf; n = 64;      break;
    case 45: src = p.whc0; dst = p.whcf; n = 64;      break;
    case 46: src = p.bhc0; dst = p.bhcf; n = 64;      break;
    case 47: src = p.whl0; dst = p.whlf; n = 8192;    break;
    case 48: src = p.bhl0; dst = p.bhlf; n = 64;      break;
    case 49: src = p.clsw0; dst = p.clswf; n = 65536; break;
    case 50: src = p.clsb0; dst = p.clsbf; n = 4;     break;
    default: return;
  }
  for (int i = tid; i < n; i += 256) dst[i] = cvload(src, i, f);
}

// ================= init kernels =================
__global__ void k_scatter(Params p) {
  for (int e = threadIdx.x; e < E_; e += 256) {
    int s = p.eidx[e], d = p.eidx[E_ + e];
    atomicAdd(&p.Ascr[s * N_ + d], p.ewf[e]);
  }
}
__global__ void k_deg(Params p) {
  int j = threadIdx.x;
  float dg = 1.f;
  for (int i = 0; i < N_; ++i) dg += p.Ascr[i * N_ + j];
  p.dinvS[j] = rsqrtf(dg);
}
__global__ void k_ant(Params p) {
  int i = blockIdx.x, j = threadIdx.x;
  float a = p.Ascr[i * N_ + j] + (i == j ? 1.f : 0.f);
  p.AnT[j * N_ + i] = p.dinvS[i] * a * p.dinvS[j];
}
__global__ void k_uv(Params p) {
  int e = threadIdx.x; if (e >= 64) return;
  float uz = 0, vz = 0, ur = 0, vr = 0, uh = 0, vh = 0;
  for (int f = 0; f < 64; ++f) {
    float wz = p.wzlf[f * 64 + e], wr = p.wrlf[f * 64 + e], wh = p.whlf[f * 64 + e];
    uz += p.wzcf[f] * wz; vz += p.bzcf[f] * wz;
    ur += p.wrcf[f] * wr; vr += p.brcf[f] * wr;
    uh += p.whcf[f] * wh; vh += p.bhcf[f] * wh;
  }
  p.uvF[0 * 64 + e] = uz; p.uvF[1 * 64 + e] = vz + p.bzlf[e];
  p.uvF[2 * 64 + e] = ur; p.uvF[3 * 64 + e] = vr + p.brlf[e];
  p.uvF[4 * 64 + e] = uh; p.uvF[5 * 64 + e] = vh + p.bhlf[e];
}

// ================= main persistent kernel =================
__global__ void __launch_bounds__(256) dtgcn_main(Params p) {
  __shared__ float s_gw[FG_ * 64];
  __shared__ u16 s_w1[64 * 64], s_w2[64 * 64];
  __shared__ float s_gb[64], s_b1[64], s_b2[64];
  __shared__ float s_uv[6 * 64];
  __shared__ float s_y[256], s_dinv[256], s_s[16];
  __shared__ __align__(16) float s_buf[4 * 16 * 68];
  __shared__ float s_col[256];

  const int b = blockIdx.x & 15;
  const int wg = blockIdx.x >> 4;
  const int tid = threadIdx.x;
  const int lane = tid & 63;
  const int wv = tid >> 6;
  const int r0 = wg * 16;

  for (int i = tid; i < FG_ * 64; i += 256) s_gw[i] = p.gwf[i];
  for (int i = tid; i < 64 * 64; i += 256) { s_w1[i] = p.w1h[i]; s_w2[i] = p.w2h[i]; }
  if (tid < 64) { s_gb[tid] = p.gbf[tid]; s_b1[tid] = p.b1f[tid]; s_b2[tid] = p.b2ff[tid]; }
  for (int i = tid; i < 6 * 64; i += 256) s_uv[i] = p.uvF[i];
  __syncthreads();

  float* XWb  = p.XW  + (size_t)b * N_ * 64;   // cross-WG: sc0sc1
  float* de1b = p.de1 + (size_t)b * N_ * 64;   // cross-WG: sc0sc1
  float* de2b = p.de2 + (size_t)b * N_ * 64;   // cross-WG: sc0sc1
  float* hb   = p.h   + (size_t)b * N_ * 64;   // WG-private: cached
  float* Msb  = p.Msum + (size_t)b * N_ * N_;  // cross-WG: atomic/sc
  float* degb = p.degsum + (size_t)b * N_;     // cross-WG: atomic/sc
  int* bar = p.bar + b * 64;                   // padded: 256 B per batch
  int bcnt = 0;

  for (int t = 0; t < T_; ++t) {
    // ---------- phase 1: XW = [win | h] @ gw ----------
    {
      const int row = r0 + wv * 4;
      float acc[4], xr[4], hr[4];
      #pragma unroll
      for (int r = 0; r < 4; ++r) {
        const int i = row + r;
        const int tx = t - (W_ - 1) + lane;
        xr[r] = (lane < W_ && tx >= 0) ? p.xf[((size_t)b * N_ + i) * T_ + tx] : 0.f;
        hr[r] = hb[i * 64 + lane];
        acc[r] = 0.f;
      }
      for (int k = 0; k < W_; ++k) {
        float gv = s_gw[k * 64 + lane];
        #pragma unroll
        for (int r = 0; r < 4; ++r) acc[r] += __shfl(xr[r], k) * gv;
      }
      for (int m = 0; m < 64; ++m) {
        float gv = s_gw[(W_ + m) * 64 + lane];
        #pragma unroll
        for (int r = 0; r < 4; ++r) acc[r] += __shfl(hr[r], m) * gv;
      }
      #pragma unroll
      for (int r = 0; r < 4; ++r) gst(&XWb[(row + r) * 64 + lane], acc[r]);
    }
    bbar(bar, bcnt);  // B1

    // ---------- phase 2: df = AnT@XW + gb ; de1/de2 = tanh(df@w1/2 + b) ----------
    {
      const int jrow = r0 + wv * 4;
      float df[4];
      #pragma unroll
      for (int r = 0; r < 4; ++r) df[r] = s_gb[lane];
      for (int ch = 0; ch < 4; ++ch) {
        // issue all 16 sc loads into regs BEFORE the sync (pipelined)
        float tmp[16];
        #pragma unroll
        for (int u = 0; u < 16; ++u) tmp[u] = gld(&XWb[ch * 4096 + u * 256 + tid]);
        float ar[4];
        #pragma unroll
        for (int r = 0; r < 4; ++r) ar[r] = p.AnT[(jrow + r) * N_ + ch * 64 + lane];
        __syncthreads();   // prev chunk fully consumed
        #pragma unroll
        for (int u = 0; u < 16; ++u) s_buf[u * 256 + tid] = tmp[u];
        __syncthreads();
        for (int m = 0; m < 64; ++m) {
          float xwv = s_buf[m * 64 + lane];
          #pragma unroll
          for (int r = 0; r < 4; ++r) df[r] += __shfl(ar[r], m) * xwv;
        }
      }
      float e1[4], e2[4];
      #pragma unroll
      for (int r = 0; r < 4; ++r) { e1[r] = s_b1[lane]; e2[r] = s_b2[lane]; }
      for (int f = 0; f < 64; ++f) {
        float w1v = b2f(s_w1[f * 64 + lane]);
        float w2v = b2f(s_w2[f * 64 + lane]);
        #pragma unroll
        for (int r = 0; r < 4; ++r) {
          float dv = __shfl(df[r], f);
          e1[r] += dv * w1v; e2[r] += dv * w2v;
        }
      }
      #pragma unroll
      for (int r = 0; r < 4; ++r) {
        gst(&de1b[(jrow + r) * 64 + lane], ftanh(e1[r]));
        gst(&de2b[(jrow + r) * 64 + lane], ftanh(e2[r]));
      }
    }
    bbar(bar, bcnt);  // B2

    // ---------- phase 3: Et (triangle), Msum/Eh ring update, degsum delta ----------
    {
      const int sidx = t % S_;
      float* Ehb = p.Eh + (size_t)(b * S_ + sidx) * N_ * N_;  // owner-stable: cached
      s_col[tid] = 0.f;
      __syncthreads();
      for (int tile = wg; tile < 136; tile += G_) {
        int I = 0, rem = tile;
        while (rem >= 16 - I) { rem -= 16 - I; ++I; }
        const int J = I + rem;
        // reg-batch the 16 sc staging loads (pipelined, overlap the sync)
        float t1[4], t2[4], t3[4], t4[4];
        #pragma unroll
        for (int u = 0; u < 4; ++u) {
          const int e = u * 256 + tid, rr = e >> 6, cc = e & 63;
          t1[u] = gld(&de1b[(I * 16 + rr) * 64 + cc]);
          t2[u] = gld(&de2b[(J * 16 + rr) * 64 + cc]);
          t3[u] = gld(&de1b[(J * 16 + rr) * 64 + cc]);
          t4[u] = gld(&de2b[(I * 16 + rr) * 64 + cc]);
        }
        __syncthreads();
        float* T1I = s_buf;        float* T2J = s_buf + 1088;
        float* T1J = s_buf + 2176; float* T2I = s_buf + 3264;
        #pragma unroll
        for (int u = 0; u < 4; ++u) {
          const int e = u * 256 + tid, rr = e >> 6, cc = e & 63;
          T1I[rr * 68 + cc] = t1[u];
          T2J[rr * 68 + cc] = t2[u];
          T1J[rr * 68 + cc] = t3[u];
          T2I[rr * 68 + cc] = t4[u];
        }
        __syncthreads();
        const int ti = tid >> 4, tj = tid & 15;
        const bool active = (I != J) || (ti < tj);
        float dcj = 0.f, dci = 0.f;
        if (active) {
          const float4* a1 = (const float4*)(T1I + ti * 68);
          const float4* b1 = (const float4*)(T2J + tj * 68);
          const float4* a2 = (const float4*)(T1J + tj * 68);
          const float4* b2 = (const float4*)(T2I + ti * 68);
          float d1 = 0.f, d2 = 0.f;
          #pragma unroll
          for (int q = 0; q < 16; ++q) {
            float4 av = a1[q], bv = b1[q];
            d1 += av.x * bv.x + av.y * bv.y + av.z * bv.z + av.w * bv.w;
            float4 cv = a2[q], dv = b2[q];
            d2 += cv.x * dv.x + cv.y * dv.y + cv.z * dv.z + cv.w * dv.w;
          }
          float d = ftanh(d1 - d2);
          float eij = fmaxf(d, 0.f), eji = fmaxf(-d, 0.f);
          const int gi = I * 16 + ti, gj = J * 16 + tj;
          const int o1 = gi * N_ + gj, o2 = gj * N_ + gi;
          float old1 = Ehb[o1], old2 = Ehb[o2];
          atomicAdd(&Msb[o1], eij - old1);   // fire-and-forget, resolves at L3
          atomicAdd(&Msb[o2], eji - old2);
          Ehb[o1] = eij; Ehb[o2] = eji;
          dcj = eij - old1; dci = eji - old2;
        }
        dcj += __shfl_xor(dcj, 16); dcj += __shfl_xor(dcj, 32);
        dci += __shfl_xor(dci, 1);  dci += __shfl_xor(dci, 2);
        dci += __shfl_xor(dci, 4);  dci += __shfl_xor(dci, 8);
        if ((lane >> 4) == 0) atomicAdd(&s_col[J * 16 + (lane & 15)], dcj);
        if ((lane & 15) == 0) atomicAdd(&s_col[I * 16 + (wv * 4 + (lane >> 4))], dci);
      }
      __syncthreads();
      atomicAdd(&degb[tid], s_col[tid]);
    }
    bbar(bar, bcnt);  // B3

    // ---------- phase 4: dinv/y, s = dinv*(Msum^T y /cnt + y), GRU ----------
    {
      const float cnt = (float)((t + 1 < S_) ? (t + 1) : S_);
      const float invc = 1.f / cnt;
      {
        float dg = 1.f + gld(&degb[tid]) * invc;
        float di = rsqrtf(dg);
        float xv = p.xf[((size_t)b * N_ + tid) * T_ + t];
        s_dinv[tid] = di;
        s_y[tid] = di * xv;
      }
      __syncthreads();
      {
        const int jj = tid & 15, c = tid >> 4;
        const int j = r0 + jj;
        float mv[16];
        #pragma unroll
        for (int k = 0; k < 16; ++k) mv[k] = gld(&Msb[(c * 16 + k) * N_ + j]);
        float part = 0.f;
        #pragma unroll
        for (int k = 0; k < 16; ++k) part += mv[k] * s_y[c * 16 + k];
        s_buf[c * 16 + jj] = part;
      }
      __syncthreads();
      if (tid < 16) {
        float tot = 0.f;
        for (int k = 0; k < 16; ++k) tot += s_buf[k * 16 + tid];
        const int j = r0 + tid;
        s_s[tid] = s_dinv[j] * (tot * invc + s_y[j]);
      }
      __syncthreads();
      const int jrow = r0 + wv * 4;
      float hreg[4], sv[4], zz[4], rr2[4];
      #pragma unroll
      for (int r = 0; r < 4; ++r) {
        hreg[r] = hb[(jrow + r) * 64 + lane];
        sv[r] = s_s[wv * 4 + r];
      }
      float4* sb4 = (float4*)s_buf;
      // z gate
      {
        const float4* wp = (const float4*)(p.wzlf + 4096);
        float4 wreg[4];
        #pragma unroll
        for (int u = 0; u < 4; ++u) wreg[u] = wp[u * 256 + tid];
        __syncthreads();
        #pragma unroll
        for (int u = 0; u < 4; ++u) sb4[u * 256 + tid] = wreg[u];
        __syncthreads();
        float a[4];
        #pragma unroll
        for (int r = 0; r < 4; ++r) a[r] = s_uv[0 * 64 + lane] * sv[r] + s_uv[1 * 64 + lane];
        for (int f = 0; f < 64; ++f) {
          float wt = s_buf[f * 64 + lane];
          #pragma unroll
          for (int r = 0; r < 4; ++r) a[r] += __shfl(hreg[r], f) * wt;
        }
        #pragma unroll
        for (int r = 0; r < 4; ++r) zz[r] = fsigm(a[r]);
      }
      // r gate
      {
        const float4* wp = (const float4*)(p.wrlf + 4096);
        float4 wreg[4];
        #pragma unroll
        for (int u = 0; u < 4; ++u) wreg[u] = wp[u * 256 + tid];
        __syncthreads();
        #pragma unroll
        for (int u = 0; u < 4; ++u) sb4[u * 256 + tid] = wreg[u];
        __syncthreads();
        float a[4];
        #pragma unroll
        for (int r = 0; r < 4; ++r) a[r] = s_uv[2 * 64 + lane] * sv[r] + s_uv[3 * 64 + lane];
        for (int f = 0; f < 64; ++f) {
          float wt = s_buf[f * 64 + lane];
          #pragma unroll
          for (int r = 0; r < 4; ++r) a[r] += __shfl(hreg[r], f) * wt;
        }
        #pragma unroll
        for (int r = 0; r < 4; ++r) rr2[r] = fsigm(a[r]);
      }
      // candidate + update
      {
        const float4* wp = (const float4*)(p.whlf + 4096);
        float4 wreg[4];
        #pragma unroll
        for (int u = 0; u < 4; ++u) wreg[u] = wp[u * 256 + tid];
        __syncthreads();
        #pragma unroll
        for (int u = 0; u < 4; ++u) sb4[u * 256 + tid] = wreg[u];
        __syncthreads();
        float hrg[4], a[4];
        #pragma unroll
        for (int r = 0; r < 4; ++r) {
          hrg[r] = hreg[r] * rr2[r];
          a[r] = s_uv[4 * 64 + lane] * sv[r] + s_uv[5 * 64 + lane];
        }
        for (int f = 0; f < 64; ++f) {
          float wt = s_buf[f * 64 + lane];
          #pragma unroll
          for (int r = 0; r < 4; ++r) a[r] += __shfl(hrg[r], f) * wt;
        }
        #pragma unroll
        for (int r = 0; r < 4; ++r) {
          float ht = ftanh(a[r]);
          float hn = zz[r] * hreg[r] + (1.f - zz[r]) * ht;
          hb[(jrow + r) * 64 + lane] = hn;
        }
      }
    }
  }
}

// ================= classifier =================
__global__ void k_cls(Params p) {
  __shared__ float red[256][4];
  const int b = blockIdx.x, i = threadIdx.x;
  const float* hr = p.h + ((size_t)b * N_ + i) * 64;
  const float* w = p.clswf + (size_t)i * 64 * 4;
  float a0 = 0, a1 = 0, a2 = 0, a3 = 0;
  for (int f = 0; f < 64; ++f) {
    float hv = hr[f];
    a0 += hv * w[f * 4 + 0]; a1 += hv * w[f * 4 + 1];
    a2 += hv * w[f * 4 + 2]; a3 += hv * w[f * 4 + 3];
  }
  red[i][0] = a0; red[i][1] = a1; red[i][2] = a2; red[i][3] = a3;
  __syncthreads();
  for (int st = 128; st > 0; st >>= 1) {
    if (i < st) {
      red[i][0] += red[i + st][0]; red[i][1] += red[i + st][1];
      red[i][2] += red[i + st][2]; red[i][3] += red[i + st][3];
    }
    __syncthreads();
  }
  if (i < 4) {
    float v = red[0][i] + p.clsbf[i];
    if (*p.flag) ((float*)p.out)[b * 4 + i] = v;
    else         ((u16*)p.out)[b * 4 + i] = f2b(v);
  }
}

extern "C" void kernel_launch(void* const* d_in, const int* in_sizes, int n_in,
                              void* d_out, int out_size, void* d_ws, size_t ws_size,
                              hipStream_t stream) {
  float* w = (float*)d_ws;
  size_t o = 0;
  auto alloc = [&](size_t n) { float* r = w + o; o += (n + 63) & ~(size_t)63; return r; };
  float* xf    = alloc(262144);
  float* ewf   = alloc(E_);
  float* gwf   = alloc(FG_ * 64);
  float* gbf   = alloc(64);
  float* b1f   = alloc(64);
  float* b2ff  = alloc(64);
  float* wzcf  = alloc(64); float* bzcf = alloc(64); float* wzlf = alloc(8192); float* bzlf = alloc(64);
  float* wrcf  = alloc(64); float* brcf = alloc(64); float* wrlf = alloc(8192); float* brlf = alloc(64);
  float* whcf  = alloc(64); float* bhcf = alloc(64); float* whlf = alloc(8192); float* bhlf = alloc(64);
  float* clswf = alloc(65536); float* clsbf = alloc(64);
  u16* w1h = (u16*)alloc(2048);
  u16* w2h = (u16*)alloc(2048);
  int* flag = (int*)alloc(64);
  float* AnT   = alloc(65536);
  float* dinvS = alloc(256);
  float* uvF   = alloc(384);
  float* XW    = alloc((size_t)B_ * N_ * 64);
  float* de1   = alloc((size_t)B_ * N_ * 64);
  float* de2   = alloc((size_t)B_ * N_ * 64);
  const size_t zero_off = o;
  float* Ascr  = alloc((size_t)N_ * N_);
  float* h     = alloc((size_t)B_ * N_ * 64);
  float* Msum  = alloc((size_t)B_ * N_ * N_);
  float* degs  = alloc((size_t)B_ * N_);
  int*   bar   = (int*)alloc(B_ * 64);   // 64 ints (256 B) per batch
  float* Eh    = alloc((size_t)B_ * S_ * N_ * N_);
  if (ws_size < o * sizeof(float)) return;

  (void)hipMemsetAsync(w + zero_off, 0, (o - zero_off) * sizeof(float), stream);

  Params p;
  p.x0  = d_in[0];  p.ew0 = d_in[1];
  p.gw0 = d_in[2];  p.gb0 = d_in[3];
  p.w10 = d_in[4];  p.b10 = d_in[5];
  p.w20 = d_in[6];  p.b20 = d_in[7];
  p.wzc0 = d_in[8];  p.bzc0 = d_in[9];  p.wzl0 = d_in[10]; p.bzl0 = d_in[11];
  p.wrc0 = d_in[12]; p.brc0 = d_in[13]; p.wrl0 = d_in[14]; p.brl0 = d_in[15];
  p.whc0 = d_in[16]; p.bhc0 = d_in[17]; p.whl0 = d_in[18]; p.bhl0 = d_in[19];
  p.clsw0 = d_in[20]; p.clsb0 = d_in[21];
  p.eidx = (const int*)d_in[22];
  p.xf = xf; p.ewf = ewf; p.gwf = gwf; p.gbf = gbf; p.b1f = b1f; p.b2ff = b2ff;
  p.wzcf = wzcf; p.bzcf = bzcf; p.wzlf = wzlf; p.bzlf = bzlf;
  p.wrcf = wrcf; p.brcf = brcf; p.wrlf = wrlf; p.brlf = brlf;
  p.whcf = whcf; p.bhcf = bhcf; p.whlf = whlf; p.bhlf = bhlf;
  p.clswf = clswf; p.clsbf = clsbf; p.w1h = w1h; p.w2h = w2h;
  p.AnT = AnT; p.dinvS = dinvS; p.uvF = uvF; p.XW = XW; p.de1 = de1; p.de2 = de2;
  p.h = h; p.Msum = Msum; p.degsum = degs; p.Eh = Eh; p.Ascr = Ascr;
  p.bar = bar; p.flag = flag; p.out = d_out;

  k_detect<<<1, 64, 0, stream>>>(p);
  k_convert<<<53, 256, 0, stream>>>(p);
  k_scatter<<<1, 256, 0, stream>>>(p);
  k_deg<<<1, 256, 0, stream>>>(p);
  k_ant<<<N_, 256, 0, stream>>>(p);
  k_uv<<<1, 64, 0, stream>>>(p);

  void* args[] = { &p };
  hipError_t ce = hipLaunchCooperativeKernel((const void*)dtgcn_main,
                                             dim3(B_ * G_), dim3(256), args, 0, stream);
  if (ce != hipSuccess) {
    (void)hipGetLastError();
    dtgcn_main<<<dim3(B_ * G_), dim3(256), 0, stream>>>(p);
  }

  k_cls<<<B_, 256, 0, stream>>>(p);
}

// Round 6
// 3075.248 us; speedup vs baseline: 7.8799x; 1.4199x over previous
//
#include <hip/hip_runtime.h>
#include <hip/hip_bf16.h>

// DTGCN: B=16,N=256,T=64,W=12,H=64,ED=64,S=5,C=4,E=2048, FG=76
// R6: broadcast-GEMV rewrite. All weights LDS-resident; XW in registers;
// P3 row-strip ownership (Msum in LDS + gst mirror, Eh private);
// h register-resident with LDS transpose. 3 fence-free barriers/step.

typedef unsigned short u16;
typedef unsigned int u32;

#define B_ 16
#define N_ 256
#define T_ 64
#define W_ 12
#define S_ 5
#define E_ 2048
#define FG_ 76
#define G_ 16   // workgroups per batch

__device__ __forceinline__ float b2f(u16 u) {
  union { u32 i; float f; } v; v.i = ((u32)u) << 16; return v.f;
}
__device__ __forceinline__ u16 f2b(float f) {
  union { float f; u32 i; } v; v.f = f;
  u32 x = v.i; x += 0x7fff + ((x >> 16) & 1); return (u16)(x >> 16);
}
__device__ __forceinline__ float ftanh(float x) {
  float e = __expf(-2.f * fabsf(x));
  float t = (1.f - e) / (1.f + e);
  return x < 0.f ? -t : t;
}
__device__ __forceinline__ float fsigm(float x) { return 1.f / (1.f + __expf(-x)); }
__device__ __forceinline__ float cvload(const void* p, int i, int f) {
  return f ? ((const float*)p)[i] : b2f(((const u16*)p)[i]);
}
__device__ __forceinline__ float gld(const float* p) {
  return __hip_atomic_load(p, __ATOMIC_RELAXED, __HIP_MEMORY_SCOPE_SYSTEM);
}
__device__ __forceinline__ void gst(float* p, float v) {
  __hip_atomic_store(p, v, __ATOMIC_RELAXED, __HIP_MEMORY_SCOPE_SYSTEM);
}

struct Params {
  const void *x0, *ew0, *gw0, *gb0, *w10, *b10, *w20, *b20;
  const void *wzc0, *bzc0, *wzl0, *bzl0, *wrc0, *brc0, *wrl0, *brl0;
  const void *whc0, *bhc0, *whl0, *bhl0, *clsw0, *clsb0;
  const int* eidx;
  float *xf, *ewf, *gwf, *gbf, *b1f, *b2ff;
  float *wzcf, *bzcf, *wzlf, *bzlf, *wrcf, *brcf, *wrlf, *brlf;
  float *whcf, *bhcf, *whlf, *bhlf, *clswf, *clsbf;
  u16 *w1h, *w2h;
  float *AnT, *dinvS, *uvF, *XW, *de1, *de2, *h, *Msum, *degsum, *Eh, *Ascr;
  int *bar, *flag;
  void* out;
};

__device__ __forceinline__ void bbar(int* ctr, int& cnt) {
  ++cnt;
  __syncthreads();   // drains vmcnt: all prior sc stores/atomics at coherence pt
  if (threadIdx.x == 0) {
    __hip_atomic_fetch_add(ctr, 1, __ATOMIC_RELAXED, __HIP_MEMORY_SCOPE_SYSTEM);
    const int target = cnt * G_;
    while (__hip_atomic_load(ctr, __ATOMIC_RELAXED, __HIP_MEMORY_SCOPE_SYSTEM) < target)
      __builtin_amdgcn_s_sleep(1);
  }
  __syncthreads();
}

// ================= dtype detect + convert =================
__global__ void k_detect(Params p) {
  if (threadIdx.x == 0) {
    const u16* q = (const u16*)p.x0;
    int c = 0;
    for (int i = 0; i < 256; ++i) {
      int ex = (q[i] >> 7) & 0xff;
      c += (ex >= 110 && ex <= 135);
    }
    *p.flag = (c < 200) ? 1 : 0;  // 1 = inputs are fp32
  }
}

__global__ void k_convert(Params p) {
  const int f = *p.flag;
  const int blk = blockIdx.x, tid = threadIdx.x;
  if (blk < 32) {
    const int base = blk * 8192;
    for (int i = tid; i < 8192; i += 256) p.xf[base + i] = cvload(p.x0, base + i, f);
    return;
  }
  if (blk == 51) { for (int i = tid; i < 4096; i += 256) p.w1h[i] = f ? f2b(((const float*)p.w10)[i]) : ((const u16*)p.w10)[i]; return; }
  if (blk == 52) { for (int i = tid; i < 4096; i += 256) p.w2h[i] = f ? f2b(((const float*)p.w20)[i]) : ((const u16*)p.w20)[i]; return; }
  const void* src = nullptr; float* dst = nullptr; int n = 0;
  switch (blk) {
    case 32: src = p.ew0;  dst = p.ewf;  n = E_;      break;
    case 33: src = p.gw0;  dst = p.gwf;  n = FG_ * 64; break;
    case 34: src = p.gb0;  dst = p.gbf;  n = 64;      break;
    case 35: src = p.b10;  dst = p.b1f;  n = 64;      break;
    case 36: src = p.b20;  dst = p.b2ff; n = 64;      break;
    case 37: src = p.wzc0; dst = p.wzcf; n = 64;      break;
    case 38: src = p.bzc0; dst = p.bzcf; n = 64;      break;
    case 39: src = p.wzl0; dst = p.wzlf; n = 8192;    break;
    case 40: src = p.bzl0; dst = p.bzlf; n = 64;      break;
    case 41: src = p.wrc0; dst = p.wrcf; n = 64;      break;
    case 42: src = p.brc0; dst = p.brcf; n = 64;      break;
    case 43: src = p.wrl0; dst = p.wrlf; n = 8192;    break;
    case 44: src = p.brl0; dst = p.brlf; n = 64;      break;
    case 45: src = p.whc0; dst = p.whcf; n = 64;      break;
    case 46: src = p.bhc0; dst = p.bhcf; n = 64;      break;
    case 47: src = p.whl0; dst = p.whlf; n = 8192;    break;
    case 48: src = p.bhl0; dst = p.bhlf; n = 64;      break;
    case 49: src = p.clsw0; dst = p.clswf; n = 65536; break;
    case 50: src = p.clsb0; dst = p.clsbf; n = 4;     break;
    default: return;
  }
  for (int i = tid; i < n; i += 256) dst[i] = cvload(src, i, f);
}

// ================= init kernels =================
__global__ void k_scatter(Params p) {
  for (int e = threadIdx.x; e < E_; e += 256) {
    int s = p.eidx[e], d = p.eidx[E_ + e];
    atomicAdd(&p.Ascr[s * N_ + d], p.ewf[e]);
  }
}
__global__ void k_deg(Params p) {
  int j = threadIdx.x;
  float dg = 1.f;
  for (int i = 0; i < N_; ++i) dg += p.Ascr[i * N_ + j];
  p.dinvS[j] = rsqrtf(dg);
}
__global__ void k_ant(Params p) {
  int i = blockIdx.x, j = threadIdx.x;
  float a = p.Ascr[i * N_ + j] + (i == j ? 1.f : 0.f);
  p.AnT[j * N_ + i] = p.dinvS[i] * a * p.dinvS[j];
}
__global__ void k_uv(Params p) {
  int e = threadIdx.x; if (e >= 64) return;
  float uz = 0, vz = 0, ur = 0, vr = 0, uh = 0, vh = 0;
  for (int f = 0; f < 64; ++f) {
    float wz = p.wzlf[f * 64 + e], wr = p.wrlf[f * 64 + e], wh = p.whlf[f * 64 + e];
    uz += p.wzcf[f] * wz; vz += p.bzcf[f] * wz;
    ur += p.wrcf[f] * wr; vr += p.brcf[f] * wr;
    uh += p.whcf[f] * wh; vh += p.bhcf[f] * wh;
  }
  p.uvF[0 * 64 + e] = uz; p.uvF[1 * 64 + e] = vz + p.bzlf[e];
  p.uvF[2 * 64 + e] = ur; p.uvF[3 * 64 + e] = vr + p.brlf[e];
  p.uvF[4 * 64 + e] = uh; p.uvF[5 * 64 + e] = vh + p.bhlf[e];
}

// ================= main persistent kernel =================
__global__ void __launch_bounds__(256) dtgcn_main(Params p) {
  __shared__ u16 s_gw[FG_ * 64];                 // [k][e] bf16
  __shared__ u16 s_w1[4096], s_w2[4096];         // [f][e] bf16
  __shared__ u16 s_gz[4096], s_gr[4096], s_gh[4096];  // gate W lower half [f][e]
  __shared__ float s_ant2[4096];                 // An[i][r0+jj], [i*16+jj]
  __shared__ float s_msum[4096];                 // own Msum rows [ii][j]
  __shared__ __align__(16) float s_de1I[1088], s_de2I[1088];  // [ii*68+k]
  __shared__ __align__(16) float s_hT[1024];     // h^T [k*16+ii]
  __shared__ __align__(16) float s_dfT[1024];    // df^T [k*16+ii] (also hr^T in P4)
  __shared__ __align__(16) float s_jbuf[4352];   // P2 dfp (4096) / P3 J-tiles / P4 partials
  __shared__ float s_col[256], s_y[256], s_dinv[256], s_s[16];
  __shared__ float s_gb[64], s_b1[64], s_b2[64];
  __shared__ float s_uv[384];

  const int b = blockIdx.x & 15;
  const int wg = blockIdx.x >> 4;
  const int tid = threadIdx.x;
  const int lane = tid & 63;
  const int wv = tid >> 6;
  const int r0 = wg * 16;

  // ---- one-time LDS init ----
  for (int i = tid; i < FG_ * 64; i += 256) s_gw[i] = f2b(p.gwf[i]);
  for (int i = tid; i < 4096; i += 256) {
    s_w1[i] = p.w1h[i]; s_w2[i] = p.w2h[i];
    s_gz[i] = f2b(p.wzlf[4096 + i]);
    s_gr[i] = f2b(p.wrlf[4096 + i]);
    s_gh[i] = f2b(p.whlf[4096 + i]);
    // transpose of A rows r0..r0+15: s_ant2[i*16+jj] = An[i][r0+jj] = AnT[(r0+jj)*N+i]
    s_ant2[i] = p.AnT[(r0 + (i & 15)) * N_ + (i >> 4)];
    s_msum[i] = 0.f;
  }
  for (int i = tid; i < 1024; i += 256) s_hT[i] = 0.f;
  if (tid < 64) { s_gb[tid] = p.gbf[tid]; s_b1[tid] = p.b1f[tid]; s_b2[tid] = p.b2ff[tid]; }
  for (int i = tid; i < 384; i += 256) s_uv[i] = p.uvF[i];
  __syncthreads();

  float* XWb  = p.XW  + (size_t)b * N_ * 64;   // cross-WG: sc
  float* de1b = p.de1 + (size_t)b * N_ * 64;   // cross-WG: sc
  float* de2b = p.de2 + (size_t)b * N_ * 64;   // cross-WG: sc
  float* hb   = p.h   + (size_t)b * N_ * 64;   // written once at end
  float* Msb  = p.Msum + (size_t)b * N_ * N_;  // cross-WG: sc mirror
  float* degb = p.degsum + (size_t)b * N_;     // cross-WG: atomic + sc read
  int* bar = p.bar + b * 64;
  int bcnt = 0;

  float hreg[4] = {0.f, 0.f, 0.f, 0.f};        // h rows r0+wv*4+r, col lane

  for (int t = 0; t < T_; ++t) {
    // ---------- P1: XW = [win | h] @ gw, own rows ----------
    {
      float acc[4], xr[4];
      const int tx = t - (W_ - 1) + lane;
      #pragma unroll
      for (int r = 0; r < 4; ++r) {
        const int row = r0 + wv * 4 + r;
        xr[r] = (lane < W_ && tx >= 0) ? p.xf[((size_t)b * N_ + row) * T_ + tx] : 0.f;
        acc[r] = 0.f;
      }
      for (int k = 0; k < W_; ++k) {
        float wt = b2f(s_gw[k * 64 + lane]);
        #pragma unroll
        for (int r = 0; r < 4; ++r) acc[r] += __shfl(xr[r], k) * wt;
      }
      for (int k = 0; k < 64; ++k) {
        float4 h4 = *(const float4*)&s_hT[k * 16 + wv * 4];
        float wt = b2f(s_gw[(W_ + k) * 64 + lane]);
        acc[0] += h4.x * wt; acc[1] += h4.y * wt;
        acc[2] += h4.z * wt; acc[3] += h4.w * wt;
      }
      #pragma unroll
      for (int r = 0; r < 4; ++r) gst(&XWb[(r0 + wv * 4 + r) * 64 + lane], acc[r]);
    }
    bbar(bar, bcnt);  // B1

    // ---------- P2: df = A^T@XW + gb ; de = tanh(df@w + b) ----------
    {
      float df[16];
      #pragma unroll
      for (int j = 0; j < 16; ++j) df[j] = 0.f;
      float tA[16], tB[16];
      #pragma unroll
      for (int u = 0; u < 16; ++u) tA[u] = gld(&XWb[u * 256 + tid]);
      for (int ch = 0; ch < 4; ++ch) {
        if (ch < 3) {
          #pragma unroll
          for (int u = 0; u < 16; ++u) tB[u] = gld(&XWb[(ch + 1) * 4096 + u * 256 + tid]);
        }
        #pragma unroll
        for (int u = 0; u < 16; ++u) {
          const int i = ch * 64 + u * 4 + wv;   // row held in tA[u]
          const float4* ap = (const float4*)&s_ant2[i * 16];
          float4 a0 = ap[0], a1 = ap[1], a2 = ap[2], a3 = ap[3];
          float xv = tA[u];
          df[0]  += a0.x * xv; df[1]  += a0.y * xv; df[2]  += a0.z * xv; df[3]  += a0.w * xv;
          df[4]  += a1.x * xv; df[5]  += a1.y * xv; df[6]  += a1.z * xv; df[7]  += a1.w * xv;
          df[8]  += a2.x * xv; df[9]  += a2.y * xv; df[10] += a2.z * xv; df[11] += a2.w * xv;
          df[12] += a3.x * xv; df[13] += a3.y * xv; df[14] += a3.z * xv; df[15] += a3.w * xv;
        }
        if (ch < 3) {
          #pragma unroll
          for (int u = 0; u < 16; ++u) tA[u] = tB[u];
        }
      }
      // wave partials -> s_jbuf[(wv*16+jj)*64 + lane]
      #pragma unroll
      for (int j = 0; j < 16; ++j) s_jbuf[(wv * 16 + j) * 64 + lane] = df[j];
      __syncthreads();
      // reduce 4 partials + bias -> s_dfT[e*16+jj]
      {
        const int jj = tid >> 4, eb = (tid & 15) * 4;
        #pragma unroll
        for (int q = 0; q < 4; ++q) {
          const int e = eb + q;
          float v = s_gb[e];
          v += s_jbuf[(0 * 16 + jj) * 64 + e];
          v += s_jbuf[(1 * 16 + jj) * 64 + e];
          v += s_jbuf[(2 * 16 + jj) * 64 + e];
          v += s_jbuf[(3 * 16 + jj) * 64 + e];
          s_dfT[e * 16 + jj] = v;
        }
      }
      __syncthreads();
      // de1/de2 for own rows
      float e1[4], e2[4];
      #pragma unroll
      for (int r = 0; r < 4; ++r) { e1[r] = s_b1[lane]; e2[r] = s_b2[lane]; }
      for (int f = 0; f < 64; ++f) {
        float4 d4 = *(const float4*)&s_dfT[f * 16 + wv * 4];
        float w1v = b2f(s_w1[f * 64 + lane]);
        float w2v = b2f(s_w2[f * 64 + lane]);
        e1[0] += d4.x * w1v; e1[1] += d4.y * w1v; e1[2] += d4.z * w1v; e1[3] += d4.w * w1v;
        e2[0] += d4.x * w2v; e2[1] += d4.y * w2v; e2[2] += d4.z * w2v; e2[3] += d4.w * w2v;
      }
      #pragma unroll
      for (int r = 0; r < 4; ++r) {
        const int ii = wv * 4 + r;
        float v1 = ftanh(e1[r]), v2 = ftanh(e2[r]);
        s_de1I[ii * 68 + lane] = v1;
        s_de2I[ii * 68 + lane] = v2;
        gst(&de1b[(r0 + ii) * 64 + lane], v1);
        gst(&de2b[(r0 + ii) * 64 + lane], v2);
      }
    }
    bbar(bar, bcnt);  // B2

    // ---------- P3: Et row-strip (own 16 rows x 256 cols), Eh/Msum/deg ----------
    {
      const int sidx = t % S_;
      float* Ehr = p.Eh + (size_t)(b * S_ + sidx) * N_ * N_;
      s_col[tid] = 0.f;
      float* s_j1 = s_jbuf;          // [32][68]
      float* s_j2 = s_jbuf + 2176;
      const int ti = tid >> 4, g = tid & 15;
      for (int jt = 0; jt < 8; ++jt) {
        float j1[8], j2[8];
        #pragma unroll
        for (int u = 0; u < 8; ++u) {
          const int e = u * 256 + tid, jr = e >> 6, k = e & 63;
          j1[u] = gld(&de1b[(jt * 32 + jr) * 64 + k]);
          j2[u] = gld(&de2b[(jt * 32 + jr) * 64 + k]);
        }
        __syncthreads();   // previous tile fully consumed (also covers s_col zero)
        #pragma unroll
        for (int u = 0; u < 8; ++u) {
          const int e = u * 256 + tid, jr = e >> 6, k = e & 63;
          s_j1[jr * 68 + k] = j1[u];
          s_j2[jr * 68 + k] = j2[u];
        }
        __syncthreads();
        // pair (i = r0+ti, j = jt*32 + 2g/2g+1)
        const float4* A1 = (const float4*)&s_de1I[ti * 68];
        const float4* A2 = (const float4*)&s_de2I[ti * 68];
        const float4* B2a = (const float4*)&s_j2[(2 * g) * 68];
        const float4* B2b = (const float4*)&s_j2[(2 * g + 1) * 68];
        const float4* B1a = (const float4*)&s_j1[(2 * g) * 68];
        const float4* B1b = (const float4*)&s_j1[(2 * g + 1) * 68];
        float d1a = 0.f, d2a = 0.f, d1b = 0.f, d2b = 0.f;
        #pragma unroll
        for (int q = 0; q < 16; ++q) {
          float4 x1 = A1[q], x2 = A2[q];
          float4 ya = B2a[q], yb = B2b[q], za = B1a[q], zb = B1b[q];
          d1a += x1.x * ya.x + x1.y * ya.y + x1.z * ya.z + x1.w * ya.w;
          d1b += x1.x * yb.x + x1.y * yb.y + x1.z * yb.z + x1.w * yb.w;
          d2a += za.x * x2.x + za.y * x2.y + za.z * x2.z + za.w * x2.w;
          d2b += zb.x * x2.x + zb.y * x2.y + zb.z * x2.z + zb.w * x2.w;
        }
        const int gjA = jt * 32 + 2 * g, gjB = gjA + 1;
        const int grow = (r0 + ti) * N_;
        float DA = ftanh(d1a - d2a), DB = ftanh(d1b - d2b);
        float eA = fmaxf(DA, 0.f), eB = fmaxf(DB, 0.f);
        float oldA = Ehr[grow + gjA], oldB = Ehr[grow + gjB];
        float dA = eA - oldA, dB = eB - oldB;
        Ehr[grow + gjA] = eA; Ehr[grow + gjB] = eB;
        float mA = s_msum[ti * 256 + gjA] + dA;
        float mB = s_msum[ti * 256 + gjB] + dB;
        s_msum[ti * 256 + gjA] = mA; s_msum[ti * 256 + gjB] = mB;
        gst(&Msb[grow + gjA], mA); gst(&Msb[grow + gjB], mB);
        // column-delta reduce over ti (lane>>4 within wave = 4 ti's)
        dA += __shfl_xor(dA, 16); dA += __shfl_xor(dA, 32);
        dB += __shfl_xor(dB, 16); dB += __shfl_xor(dB, 32);
        if (lane < 16) {
          atomicAdd(&s_col[jt * 32 + 2 * lane], dA);
          atomicAdd(&s_col[jt * 32 + 2 * lane + 1], dB);
        }
      }
      __syncthreads();
      atomicAdd(&degb[tid], s_col[tid]);
    }
    bbar(bar, bcnt);  // B3

    // ---------- P4: dinv/y, s, GRU ----------
    {
      const float cnt = (float)((t + 1 < S_) ? (t + 1) : S_);
      const float invc = 1.f / cnt;
      {
        float dg = 1.f + gld(&degb[tid]) * invc;
        float di = rsqrtf(dg);
        float xv = p.xf[((size_t)b * N_ + tid) * T_ + t];
        s_dinv[tid] = di;
        s_y[tid] = di * xv;
      }
      __syncthreads();
      {
        const int jj = tid & 15, c = tid >> 4;
        const int j = r0 + jj;
        float mv[16];
        #pragma unroll
        for (int k = 0; k < 16; ++k) mv[k] = gld(&Msb[(c * 16 + k) * N_ + j]);
        float part = 0.f;
        #pragma unroll
        for (int k = 0; k < 16; ++k) part += mv[k] * s_y[c * 16 + k];
        s_jbuf[c * 16 + jj] = part;
      }
      __syncthreads();
      if (tid < 16) {
        float tot = 0.f;
        for (int k = 0; k < 16; ++k) tot += s_jbuf[k * 16 + tid];
        const int j = r0 + tid;
        s_s[tid] = s_dinv[j] * (tot * invc + s_y[j]);
      }
      __syncthreads();
      float sv[4], zz[4], rr2[4];
      #pragma unroll
      for (int r = 0; r < 4; ++r) sv[r] = s_s[wv * 4 + r];
      // z gate
      {
        float a[4];
        #pragma unroll
        for (int r = 0; r < 4; ++r) a[r] = s_uv[0 * 64 + lane] * sv[r] + s_uv[1 * 64 + lane];
        for (int f = 0; f < 64; ++f) {
          float4 h4 = *(const float4*)&s_hT[f * 16 + wv * 4];
          float wt = b2f(s_gz[f * 64 + lane]);
          a[0] += h4.x * wt; a[1] += h4.y * wt; a[2] += h4.z * wt; a[3] += h4.w * wt;
        }
        #pragma unroll
        for (int r = 0; r < 4; ++r) zz[r] = fsigm(a[r]);
      }
      // r gate
      {
        float a[4];
        #pragma unroll
        for (int r = 0; r < 4; ++r) a[r] = s_uv[2 * 64 + lane] * sv[r] + s_uv[3 * 64 + lane];
        for (int f = 0; f < 64; ++f) {
          float4 h4 = *(const float4*)&s_hT[f * 16 + wv * 4];
          float wt = b2f(s_gr[f * 64 + lane]);
          a[0] += h4.x * wt; a[1] += h4.y * wt; a[2] += h4.z * wt; a[3] += h4.w * wt;
        }
        #pragma unroll
        for (int r = 0; r < 4; ++r) rr2[r] = fsigm(a[r]);
      }
      // candidate: stage (h*r)^T into s_dfT
      {
        float4 hr4;
        hr4.x = hreg[0] * rr2[0]; hr4.y = hreg[1] * rr2[1];
        hr4.z = hreg[2] * rr2[2]; hr4.w = hreg[3] * rr2[3];
        *(float4*)&s_dfT[lane * 16 + wv * 4] = hr4;
      }
      __syncthreads();
      {
        float a[4];
        #pragma unroll
        for (int r = 0; r < 4; ++r) a[r] = s_uv[4 * 64 + lane] * sv[r] + s_uv[5 * 64 + lane];
        for (int f = 0; f < 64; ++f) {
          float4 h4 = *(const float4*)&s_dfT[f * 16 + wv * 4];
          float wt = b2f(s_gh[f * 64 + lane]);
          a[0] += h4.x * wt; a[1] += h4.y * wt; a[2] += h4.z * wt; a[3] += h4.w * wt;
        }
        #pragma unroll
        for (int r = 0; r < 4; ++r) {
          float ht = ftanh(a[r]);
          hreg[r] = zz[r] * hreg[r] + (1.f - zz[r]) * ht;
        }
      }
      // publish h^T for next step (and global h at the end)
      {
        float4 h4;
        h4.x = hreg[0]; h4.y = hreg[1]; h4.z = hreg[2]; h4.w = hreg[3];
        *(float4*)&s_hT[lane * 16 + wv * 4] = h4;
      }
      if (t == T_ - 1) {
        #pragma unroll
        for (int r = 0; r < 4; ++r) hb[(r0 + wv * 4 + r) * 64 + lane] = hreg[r];
      }
      __syncthreads();   // s_hT visible to P1(t+1)
    }
  }
}

// ================= classifier =================
__global__ void k_cls(Params p) {
  __shared__ float red[256][4];
  const int b = blockIdx.x, i = threadIdx.x;
  const float* hr = p.h + ((size_t)b * N_ + i) * 64;
  const float* w = p.clswf + (size_t)i * 64 * 4;
  float a0 = 0, a1 = 0, a2 = 0, a3 = 0;
  for (int f = 0; f < 64; ++f) {
    float hv = hr[f];
    a0 += hv * w[f * 4 + 0]; a1 += hv * w[f * 4 + 1];
    a2 += hv * w[f * 4 + 2]; a3 += hv * w[f * 4 + 3];
  }
  red[i][0] = a0; red[i][1] = a1; red[i][2] = a2; red[i][3] = a3;
  __syncthreads();
  for (int st = 128; st > 0; st >>= 1) {
    if (i < st) {
      red[i][0] += red[i + st][0]; red[i][1] += red[i + st][1];
      red[i][2] += red[i + st][2]; red[i][3] += red[i + st][3];
    }
    __syncthreads();
  }
  if (i < 4) {
    float v = red[0][i] + p.clsbf[i];
    if (*p.flag) ((float*)p.out)[b * 4 + i] = v;
    else         ((u16*)p.out)[b * 4 + i] = f2b(v);
  }
}

extern "C" void kernel_launch(void* const* d_in, const int* in_sizes, int n_in,
                              void* d_out, int out_size, void* d_ws, size_t ws_size,
                              hipStream_t stream) {
  float* w = (float*)d_ws;
  size_t o = 0;
  auto alloc = [&](size_t n) { float* r = w + o; o += (n + 63) & ~(size_t)63; return r; };
  float* xf    = alloc(262144);
  float* ewf   = alloc(E_);
  float* gwf   = alloc(FG_ * 64);
  float* gbf   = alloc(64);
  float* b1f   = alloc(64);
  float* b2ff  = alloc(64);
  float* wzcf  = alloc(64); float* bzcf = alloc(64); float* wzlf = alloc(8192); float* bzlf = alloc(64);
  float* wrcf  = alloc(64); float* brcf = alloc(64); float* wrlf = alloc(8192); float* brlf = alloc(64);
  float* whcf  = alloc(64); float* bhcf = alloc(64); float* whlf = alloc(8192); float* bhlf = alloc(64);
  float* clswf = alloc(65536); float* clsbf = alloc(64);
  u16* w1h = (u16*)alloc(2048);
  u16* w2h = (u16*)alloc(2048);
  int* flag = (int*)alloc(64);
  float* AnT   = alloc(65536);
  float* dinvS = alloc(256);
  float* uvF   = alloc(384);
  float* XW    = alloc((size_t)B_ * N_ * 64);
  float* de1   = alloc((size_t)B_ * N_ * 64);
  float* de2   = alloc((size_t)B_ * N_ * 64);
  const size_t zero_off = o;
  float* Ascr  = alloc((size_t)N_ * N_);
  float* h     = alloc((size_t)B_ * N_ * 64);
  float* Msum  = alloc((size_t)B_ * N_ * N_);
  float* degs  = alloc((size_t)B_ * N_);
  int*   bar   = (int*)alloc(B_ * 64);
  float* Eh    = alloc((size_t)B_ * S_ * N_ * N_);
  if (ws_size < o * sizeof(float)) return;

  (void)hipMemsetAsync(w + zero_off, 0, (o - zero_off) * sizeof(float), stream);

  Params p;
  p.x0  = d_in[0];  p.ew0 = d_in[1];
  p.gw0 = d_in[2];  p.gb0 = d_in[3];
  p.w10 = d_in[4];  p.b10 = d_in[5];
  p.w20 = d_in[6];  p.b20 = d_in[7];
  p.wzc0 = d_in[8];  p.bzc0 = d_in[9];  p.wzl0 = d_in[10]; p.bzl0 = d_in[11];
  p.wrc0 = d_in[12]; p.brc0 = d_in[13]; p.wrl0 = d_in[14]; p.brl0 = d_in[15];
  p.whc0 = d_in[16]; p.bhc0 = d_in[17]; p.whl0 = d_in[18]; p.bhl0 = d_in[19];
  p.clsw0 = d_in[20]; p.clsb0 = d_in[21];
  p.eidx = (const int*)d_in[22];
  p.xf = xf; p.ewf = ewf; p.gwf = gwf; p.gbf = gbf; p.b1f = b1f; p.b2ff = b2ff;
  p.wzcf = wzcf; p.bzcf = bzcf; p.wzlf = wzlf; p.bzlf = bzlf;
  p.wrcf = wrcf; p.brcf = brcf; p.wrlf = wrlf; p.brlf = brlf;
  p.whcf = whcf; p.bhcf = bhcf; p.whlf = whlf; p.bhlf = bhlf;
  p.clswf = clswf; p.clsbf = clsbf; p.w1h = w1h; p.w2h = w2h;
  p.AnT = AnT; p.dinvS = dinvS; p.uvF = uvF; p.XW = XW; p.de1 = de1; p.de2 = de2;
  p.h = h; p.Msum = Msum; p.degsum = degs; p.Eh = Eh; p.Ascr = Ascr;
  p.bar = bar; p.flag = flag; p.out = d_out;

  k_detect<<<1, 64, 0, stream>>>(p);
  k_convert<<<53, 256, 0, stream>>>(p);
  k_scatter<<<1, 256, 0, stream>>>(p);
  k_deg<<<1, 256, 0, stream>>>(p);
  k_ant<<<N_, 256, 0, stream>>>(p);
  k_uv<<<1, 64, 0, stream>>>(p);

  void* args[] = { &p };
  hipError_t ce = hipLaunchCooperativeKernel((const void*)dtgcn_main,
                                             dim3(B_ * G_), dim3(256), args, 0, stream);
  if (ce != hipSuccess) {
    (void)hipGetLastError();
    dtgcn_main<<<dim3(B_ * G_), dim3(256), 0, stream>>>(p);
  }

  k_cls<<<B_, 256, 0, stream>>>(p);
}

// Round 7
// 1340.885 us; speedup vs baseline: 18.0721x; 2.2934x over previous
//
#include <hip/hip_runtime.h>
#include <hip/hip_bf16.h>

// DTGCN: B=16,N=256,T=64,W=12,H=64,ED=64,S=5,C=4,E=2048, FG=76
// R7: MFMA rewrite of P1-h / P2-de / P3 / P4-gates (16x16x32 bf16).
// P2 A^T@XW stays fp32 VALU. de exchanged as packed bf16 u32. fp32 masters
// for h and XW. 3 fence-free barriers/step (sc0sc1 exchange, relaxed ctr).

typedef unsigned short u16;
typedef unsigned int u32;
typedef __attribute__((ext_vector_type(8))) short bf16x8;
typedef __attribute__((ext_vector_type(4))) float f32x4;

#define B_ 16
#define N_ 256
#define T_ 64
#define W_ 12
#define S_ 5
#define E_ 2048
#define FG_ 76
#define G_ 16

__device__ __forceinline__ float b2f(u16 u) {
  union { u32 i; float f; } v; v.i = ((u32)u) << 16; return v.f;
}
__device__ __forceinline__ u16 f2b(float f) {
  union { float f; u32 i; } v; v.f = f;
  u32 x = v.i; x += 0x7fff + ((x >> 16) & 1); return (u16)(x >> 16);
}
__device__ __forceinline__ float ftanh(float x) {
  float e = __expf(-2.f * fabsf(x));
  float t = (1.f - e) / (1.f + e);
  return x < 0.f ? -t : t;
}
__device__ __forceinline__ float fsigm(float x) { return 1.f / (1.f + __expf(-x)); }
__device__ __forceinline__ float cvload(const void* p, int i, int f) {
  return f ? ((const float*)p)[i] : b2f(((const u16*)p)[i]);
}
__device__ __forceinline__ float gld(const float* p) {
  return __hip_atomic_load(p, __ATOMIC_RELAXED, __HIP_MEMORY_SCOPE_SYSTEM);
}
__device__ __forceinline__ void gst(float* p, float v) {
  __hip_atomic_store(p, v, __ATOMIC_RELAXED, __HIP_MEMORY_SCOPE_SYSTEM);
}
__device__ __forceinline__ u32 gldu(const u32* p) {
  return __hip_atomic_load(p, __ATOMIC_RELAXED, __HIP_MEMORY_SCOPE_SYSTEM);
}
__device__ __forceinline__ void gstu(u32* p, u32 v) {
  __hip_atomic_store(p, v, __ATOMIC_RELAXED, __HIP_MEMORY_SCOPE_SYSTEM);
}
__device__ __forceinline__ f32x4 mfma16(bf16x8 a, bf16x8 b, f32x4 c) {
  return __builtin_amdgcn_mfma_f32_16x16x32_bf16(a, b, c, 0, 0, 0);
}
__device__ __forceinline__ bf16x8 ldfrag(const u16* p) { return *(const bf16x8*)p; }

struct Params {
  const void *x0, *ew0, *gw0, *gb0, *w10, *b10, *w20, *b20;
  const void *wzc0, *bzc0, *wzl0, *bzl0, *wrc0, *brc0, *wrl0, *brl0;
  const void *whc0, *bhc0, *whl0, *bhl0, *clsw0, *clsb0;
  const int* eidx;
  float *xf, *ewf, *gwf, *gbf, *b1f, *b2ff;
  float *wzcf, *bzcf, *wzlf, *bzlf, *wrcf, *brcf, *wrlf, *brlf;
  float *whcf, *bhcf, *whlf, *bhlf, *clswf, *clsbf;
  u16 *w1h, *w2h;
  float *AnT, *dinvS, *uvF, *XW, *de1, *de2, *h, *Msum, *degsum, *Eh, *Ascr;
  int *bar, *flag;
  void* out;
};

__device__ __forceinline__ void bbar(int* ctr, int& cnt) {
  ++cnt;
  __syncthreads();
  if (threadIdx.x == 0) {
    __hip_atomic_fetch_add(ctr, 1, __ATOMIC_RELAXED, __HIP_MEMORY_SCOPE_SYSTEM);
    const int target = cnt * G_;
    while (__hip_atomic_load(ctr, __ATOMIC_RELAXED, __HIP_MEMORY_SCOPE_SYSTEM) < target)
      __builtin_amdgcn_s_sleep(1);
  }
  __syncthreads();
}

// ================= dtype detect + convert =================
__global__ void k_detect(Params p) {
  if (threadIdx.x == 0) {
    const u16* q = (const u16*)p.x0;
    int c = 0;
    for (int i = 0; i < 256; ++i) {
      int ex = (q[i] >> 7) & 0xff;
      c += (ex >= 110 && ex <= 135);
    }
    *p.flag = (c < 200) ? 1 : 0;
  }
}

__global__ void k_convert(Params p) {
  const int f = *p.flag;
  const int blk = blockIdx.x, tid = threadIdx.x;
  if (blk < 32) {
    const int base = blk * 8192;
    for (int i = tid; i < 8192; i += 256) p.xf[base + i] = cvload(p.x0, base + i, f);
    return;
  }
  if (blk == 51) { for (int i = tid; i < 4096; i += 256) p.w1h[i] = f ? f2b(((const float*)p.w10)[i]) : ((const u16*)p.w10)[i]; return; }
  if (blk == 52) { for (int i = tid; i < 4096; i += 256) p.w2h[i] = f ? f2b(((const float*)p.w20)[i]) : ((const u16*)p.w20)[i]; return; }
  const void* src = nullptr; float* dst = nullptr; int n = 0;
  switch (blk) {
    case 32: src = p.ew0;  dst = p.ewf;  n = E_;      break;
    case 33: src = p.gw0;  dst = p.gwf;  n = FG_ * 64; break;
    case 34: src = p.gb0;  dst = p.gbf;  n = 64;      break;
    case 35: src = p.b10;  dst = p.b1f;  n = 64;      break;
    case 36: src = p.b20;  dst = p.b2ff; n = 64;      break;
    case 37: src = p.wzc0; dst = p.wzcf; n = 64;      break;
    case 38: src = p.bzc0; dst = p.bzcf; n = 64;      break;
    case 39: src = p.wzl0; dst = p.wzlf; n = 8192;    break;
    case 40: src = p.bzl0; dst = p.bzlf; n = 64;      break;
    case 41: src = p.wrc0; dst = p.wrcf; n = 64;      break;
    case 42: src = p.brc0; dst = p.brcf; n = 64;      break;
    case 43: src = p.wrl0; dst = p.wrlf; n = 8192;    break;
    case 44: src = p.brl0; dst = p.brlf; n = 64;      break;
    case 45: src = p.whc0; dst = p.whcf; n = 64;      break;
    case 46: src = p.bhc0; dst = p.bhcf; n = 64;      break;
    case 47: src = p.whl0; dst = p.whlf; n = 8192;    break;
    case 48: src = p.bhl0; dst = p.bhlf; n = 64;      break;
    case 49: src = p.clsw0; dst = p.clswf; n = 65536; break;
    case 50: src = p.clsb0; dst = p.clsbf; n = 4;     break;
    default: return;
  }
  for (int i = tid; i < n; i += 256) dst[i] = cvload(src, i, f);
}

// ================= init kernels =================
__global__ void k_scatter(Params p) {
  for (int e = threadIdx.x; e < E_; e += 256) {
    int s = p.eidx[e], d = p.eidx[E_ + e];
    atomicAdd(&p.Ascr[s * N_ + d], p.ewf[e]);
  }
}
__global__ void k_deg(Params p) {
  int j = threadIdx.x;
  float dg = 1.f;
  for (int i = 0; i < N_; ++i) dg += p.Ascr[i * N_ + j];
  p.dinvS[j] = rsqrtf(dg);
}
__global__ void k_ant(Params p) {
  int i = blockIdx.x, j = threadIdx.x;
  float a = p.Ascr[i * N_ + j] + (i == j ? 1.f : 0.f);
  p.AnT[j * N_ + i] = p.dinvS[i] * a * p.dinvS[j];
}
__global__ void k_uv(Params p) {
  int e = threadIdx.x; if (e >= 64) return;
  float uz = 0, vz = 0, ur = 0, vr = 0, uh = 0, vh = 0;
  for (int f = 0; f < 64; ++f) {
    float wz = p.wzlf[f * 64 + e], wr = p.wrlf[f * 64 + e], wh = p.whlf[f * 64 + e];
    uz += p.wzcf[f] * wz; vz += p.bzcf[f] * wz;
    ur += p.wrcf[f] * wr; vr += p.brcf[f] * wr;
    uh += p.whcf[f] * wh; vh += p.bhcf[f] * wh;
  }
  p.uvF[0 * 64 + e] = uz; p.uvF[1 * 64 + e] = vz + p.bzlf[e];
  p.uvF[2 * 64 + e] = ur; p.uvF[3 * 64 + e] = vr + p.brlf[e];
  p.uvF[4 * 64 + e] = uh; p.uvF[5 * 64 + e] = vh + p.bhlf[e];
}

// ================= main persistent kernel =================
__global__ void __launch_bounds__(256) dtgcn_main(Params p) {
  __shared__ __align__(16) u32 s_pool[9216];           // 36 KB: P2 partials / P3 j-halves / P4 partials
  __shared__ __align__(16) u16 s_gwT[64 * 72];         // gw rows 12..75 transposed [e][k]
  __shared__ __align__(16) u16 s_w1T[64 * 72], s_w2T[64 * 72];
  __shared__ __align__(16) u16 s_gzT[64 * 72], s_grT[64 * 72], s_ghT[64 * 72];
  __shared__ float s_gwin[12 * 64];                    // gw rows 0..11 fp32 [k][e]
  __shared__ float s_ant2[4096];                       // An[i][r0+jj] fp32
  __shared__ float s_msum[16 * 260];                   // own Msum rows, padded
  __shared__ __align__(16) u16 s_de1I[16 * 72], s_de2I[16 * 72];
  __shared__ __align__(16) u16 s_hbf[16 * 72];         // bf16 h copy [i][k]
  __shared__ __align__(16) u16 s_dfhr[16 * 72];        // df (P2) / h*r (P4)
  __shared__ float s_xwin[192];
  __shared__ float s_col[256], s_y[256], s_dinv[256], s_s[16];
  __shared__ float s_uv[384], s_gb[64], s_b1[64], s_b2[64];

  const int b = blockIdx.x & 15;
  const int wg = blockIdx.x >> 4;
  const int tid = threadIdx.x;
  const int lane = tid & 63;
  const int wv = tid >> 6;
  const int l = lane & 15;
  const int quad = lane >> 4;
  const int r0 = wg * 16;

  // ---- one-time LDS init ----
  for (int idx = tid; idx < 4096; idx += 256) {
    const int ee = idx >> 6, ff = idx & 63;
    s_gwT[ee * 72 + ff] = f2b(p.gwf[(12 + ff) * 64 + ee]);
    s_w1T[ee * 72 + ff] = p.w1h[ff * 64 + ee];
    s_w2T[ee * 72 + ff] = p.w2h[ff * 64 + ee];
    s_gzT[ee * 72 + ff] = f2b(p.wzlf[4096 + ff * 64 + ee]);
    s_grT[ee * 72 + ff] = f2b(p.wrlf[4096 + ff * 64 + ee]);
    s_ghT[ee * 72 + ff] = f2b(p.whlf[4096 + ff * 64 + ee]);
    s_ant2[idx] = p.AnT[(r0 + (idx & 15)) * N_ + (idx >> 4)];
  }
  for (int idx = tid; idx < 16 * 260; idx += 256) s_msum[idx] = 0.f;
  for (int idx = tid; idx < 16 * 72; idx += 256) s_hbf[idx] = 0;
  for (int idx = tid; idx < 768; idx += 256) s_gwin[idx] = p.gwf[idx];
  for (int idx = tid; idx < 384; idx += 256) s_uv[idx] = p.uvF[idx];
  if (tid < 64) { s_gb[tid] = p.gbf[tid]; s_b1[tid] = p.b1f[tid]; s_b2[tid] = p.b2ff[tid]; }
  __syncthreads();

  float* XWb  = p.XW  + (size_t)b * N_ * 64;        // cross-WG fp32 sc
  u32*  de1g  = (u32*)p.de1 + (size_t)b * N_ * 32;  // cross-WG packed bf16
  u32*  de2g  = (u32*)p.de2 + (size_t)b * N_ * 32;
  float* hb   = p.h   + (size_t)b * N_ * 64;
  float* Msb  = p.Msum + (size_t)b * N_ * N_;
  float* degb = p.degsum + (size_t)b * N_;
  int* bar = p.bar + b * 64;
  int bcnt = 0;

  u16* s_j1 = (u16*)s_pool;            // [128][72]
  u16* s_j2 = (u16*)(s_pool + 4608);
  float* s_part = (float*)s_pool;

  float hreg[4] = {0.f, 0.f, 0.f, 0.f};  // h[quad*4+r][wv*16+l] fp32 master

  for (int t = 0; t < T_; ++t) {
    const int e = wv * 16 + l;          // this wave's output column
    // ---------- P1: XW = [win | h] @ gw ----------
    {
      if (tid < 192) {
        const int row = tid / 12, k = tid - row * 12;
        const int tx = t - (W_ - 1) + k;
        s_xwin[row * 12 + k] = (tx >= 0) ? p.xf[((size_t)b * N_ + r0 + row) * T_ + tx] : 0.f;
      }
      __syncthreads();
      f32x4 acc;
      #pragma unroll
      for (int r = 0; r < 4; ++r) {
        float v = 0.f;
        const int i = quad * 4 + r;
        #pragma unroll
        for (int k = 0; k < W_; ++k) v += s_xwin[i * 12 + k] * s_gwin[k * 64 + e];
        acc[r] = v;
      }
      #pragma unroll
      for (int ks = 0; ks < 2; ++ks) {
        bf16x8 afr = ldfrag(&s_hbf[l * 72 + ks * 32 + quad * 8]);
        bf16x8 bfr = ldfrag(&s_gwT[e * 72 + ks * 32 + quad * 8]);
        acc = mfma16(afr, bfr, acc);
      }
      #pragma unroll
      for (int r = 0; r < 4; ++r)
        gst(&XWb[(r0 + quad * 4 + r) * 64 + e], acc[r]);
    }
    bbar(bar, bcnt);  // B1

    // ---------- P2: df = A^T@XW + gb (VALU) ; de = tanh(df@w) (MFMA) ----------
    {
      float df[16];
      #pragma unroll
      for (int j = 0; j < 16; ++j) df[j] = 0.f;
      float tA[16], tB[16];
      #pragma unroll
      for (int u = 0; u < 16; ++u) tA[u] = gld(&XWb[u * 256 + tid]);
      for (int ch = 0; ch < 4; ++ch) {
        if (ch < 3) {
          #pragma unroll
          for (int u = 0; u < 16; ++u) tB[u] = gld(&XWb[(ch + 1) * 4096 + u * 256 + tid]);
        }
        #pragma unroll
        for (int u = 0; u < 16; ++u) {
          const int i = ch * 64 + u * 4 + wv;
          const float4* ap = (const float4*)&s_ant2[i * 16];
          float4 a0 = ap[0], a1 = ap[1], a2 = ap[2], a3 = ap[3];
          float xv = tA[u];
          df[0]  += a0.x * xv; df[1]  += a0.y * xv; df[2]  += a0.z * xv; df[3]  += a0.w * xv;
          df[4]  += a1.x * xv; df[5]  += a1.y * xv; df[6]  += a1.z * xv; df[7]  += a1.w * xv;
          df[8]  += a2.x * xv; df[9]  += a2.y * xv; df[10] += a2.z * xv; df[11] += a2.w * xv;
          df[12] += a3.x * xv; df[13] += a3.y * xv; df[14] += a3.z * xv; df[15] += a3.w * xv;
        }
        if (ch < 3) {
          #pragma unroll
          for (int u = 0; u < 16; ++u) tA[u] = tB[u];
        }
      }
      #pragma unroll
      for (int j = 0; j < 16; ++j) s_part[(wv * 16 + j) * 64 + lane] = df[j];
      __syncthreads();
      // reduce 4 wave-partials + bias -> s_dfhr bf16 [j][f]
      {
        const int jj = tid >> 4, eb = (tid & 15) * 4;
        float v[4];
        #pragma unroll
        for (int q = 0; q < 4; ++q) {
          const int f = eb + q;
          float s = s_gb[f];
          s += s_part[(0 * 16 + jj) * 64 + f];
          s += s_part[(1 * 16 + jj) * 64 + f];
          s += s_part[(2 * 16 + jj) * 64 + f];
          s += s_part[(3 * 16 + jj) * 64 + f];
          v[q] = s;
        }
        u32 lo = (u32)f2b(v[0]) | ((u32)f2b(v[1]) << 16);
        u32 hi = (u32)f2b(v[2]) | ((u32)f2b(v[3]) << 16);
        *(u32*)&s_dfhr[jj * 72 + eb] = lo;
        *(u32*)&s_dfhr[jj * 72 + eb + 2] = hi;
      }
      __syncthreads();
      // de1/de2 MFMA (this wave: columns e = wv*16+l)
      {
        f32x4 E1, E2;
        #pragma unroll
        for (int r = 0; r < 4; ++r) { E1[r] = s_b1[e]; E2[r] = s_b2[e]; }
        #pragma unroll
        for (int ks = 0; ks < 2; ++ks) {
          bf16x8 afr = ldfrag(&s_dfhr[l * 72 + ks * 32 + quad * 8]);
          E1 = mfma16(afr, ldfrag(&s_w1T[e * 72 + ks * 32 + quad * 8]), E1);
          E2 = mfma16(afr, ldfrag(&s_w2T[e * 72 + ks * 32 + quad * 8]), E2);
        }
        #pragma unroll
        for (int r = 0; r < 4; ++r) {
          s_de1I[(quad * 4 + r) * 72 + e] = f2b(ftanh(E1[r]));
          s_de2I[(quad * 4 + r) * 72 + e] = f2b(ftanh(E2[r]));
        }
      }
      __syncthreads();
      // pack & publish de strips (u32 pairs, coalesced)
      #pragma unroll
      for (int q = 0; q < 2; ++q) {
        const int idx = q * 256 + tid;           // 0..511
        const int row = idx >> 5, cp = idx & 31;
        u32 v1 = (u32)s_de1I[row * 72 + cp * 2] | ((u32)s_de1I[row * 72 + cp * 2 + 1] << 16);
        u32 v2 = (u32)s_de2I[row * 72 + cp * 2] | ((u32)s_de2I[row * 72 + cp * 2 + 1] << 16);
        gstu(&de1g[(size_t)(r0 + row) * 32 + cp], v1);
        gstu(&de2g[(size_t)(r0 + row) * 32 + cp], v2);
      }
    }
    bbar(bar, bcnt);  // B2

    // ---------- P3: Et row strip via MFMA, Eh/Msum/deg ----------
    {
      const int sidx = t % S_;
      float* Ehr = p.Eh + (size_t)(b * S_ + sidx) * N_ * N_;
      bf16x8 a1[2], a2[2];
      #pragma unroll
      for (int ks = 0; ks < 2; ++ks) {
        a1[ks] = ldfrag(&s_de1I[l * 72 + ks * 32 + quad * 8]);
        a2[ks] = ldfrag(&s_de2I[l * 72 + ks * 32 + quad * 8]);
      }
      for (int jh = 0; jh < 2; ++jh) {
        u32 t1[16], t2[16];
        #pragma unroll
        for (int q = 0; q < 16; ++q) {
          const int idx = q * 256 + tid;         // 0..4095
          const int row = idx >> 5, cp = idx & 31;
          t1[q] = gldu(&de1g[(size_t)(jh * 128 + row) * 32 + cp]);
          t2[q] = gldu(&de2g[(size_t)(jh * 128 + row) * 32 + cp]);
        }
        __syncthreads();   // prev half / s_pool consumers done
        #pragma unroll
        for (int q = 0; q < 16; ++q) {
          const int idx = q * 256 + tid;
          const int row = idx >> 5, cp = idx & 31;
          *(u32*)&s_j1[row * 72 + cp * 2] = t1[q];
          *(u32*)&s_j2[row * 72 + cp * 2] = t2[q];
        }
        __syncthreads();
        #pragma unroll
        for (int jj2 = 0; jj2 < 2; ++jj2) {
          const int jloc = wv * 2 + jj2;         // 0..7 within half
          f32x4 D1 = {0.f, 0.f, 0.f, 0.f}, D2 = {0.f, 0.f, 0.f, 0.f};
          #pragma unroll
          for (int ks = 0; ks < 2; ++ks) {
            bf16x8 bf2 = ldfrag(&s_j2[(jloc * 16 + l) * 72 + ks * 32 + quad * 8]);
            bf16x8 bf1 = ldfrag(&s_j1[(jloc * 16 + l) * 72 + ks * 32 + quad * 8]);
            D1 = mfma16(a1[ks], bf2, D1);
            D2 = mfma16(a2[ks], bf1, D2);
          }
          const int j = jh * 128 + jloc * 16 + l;
          float dc = 0.f;
          #pragma unroll
          for (int r = 0; r < 4; ++r) {
            const int i = quad * 4 + r;
            float d = ftanh(D1[r] - D2[r]);
            float eN = fmaxf(d, 0.f);
            float old = Ehr[(r0 + i) * N_ + j];
            float dd = eN - old;
            Ehr[(r0 + i) * N_ + j] = eN;
            float m = s_msum[i * 260 + j] + dd;
            s_msum[i * 260 + j] = m;
            gst(&Msb[(r0 + i) * N_ + j], m);
            dc += dd;
          }
          dc += __shfl_xor(dc, 16); dc += __shfl_xor(dc, 32);
          if (lane < 16) s_col[jh * 128 + jloc * 16 + lane] = dc;
        }
      }
      __syncthreads();
      atomicAdd(&degb[tid], s_col[tid]);
    }
    bbar(bar, bcnt);  // B3

    // ---------- P4: dinv/y, s, GRU (gates via MFMA) ----------
    {
      const float cnt = (float)((t + 1 < S_) ? (t + 1) : S_);
      const float invc = 1.f / cnt;
      {
        float dg = 1.f + gld(&degb[tid]) * invc;
        float di = rsqrtf(dg);
        float xv = p.xf[((size_t)b * N_ + tid) * T_ + t];
        s_dinv[tid] = di;
        s_y[tid] = di * xv;
      }
      __syncthreads();
      {
        const int jj = tid & 15, c = tid >> 4;
        const int j = r0 + jj;
        float mv[16];
        #pragma unroll
        for (int k = 0; k < 16; ++k) mv[k] = gld(&Msb[(c * 16 + k) * N_ + j]);
        float part = 0.f;
        #pragma unroll
        for (int k = 0; k < 16; ++k) part += mv[k] * s_y[c * 16 + k];
        s_part[c * 16 + jj] = part;
      }
      __syncthreads();
      if (tid < 16) {
        float tot = 0.f;
        for (int k = 0; k < 16; ++k) tot += s_part[k * 16 + tid];
        const int j = r0 + tid;
        s_s[tid] = s_dinv[j] * (tot * invc + s_y[j]);
      }
      __syncthreads();
      float sv[4];
      #pragma unroll
      for (int r = 0; r < 4; ++r) sv[r] = s_s[quad * 4 + r];
      // z gate
      f32x4 az;
      #pragma unroll
      for (int r = 0; r < 4; ++r) az[r] = s_uv[0 * 64 + e] * sv[r] + s_uv[1 * 64 + e];
      #pragma unroll
      for (int ks = 0; ks < 2; ++ks) {
        bf16x8 afr = ldfrag(&s_hbf[l * 72 + ks * 32 + quad * 8]);
        az = mfma16(afr, ldfrag(&s_gzT[e * 72 + ks * 32 + quad * 8]), az);
      }
      float zz[4];
      #pragma unroll
      for (int r = 0; r < 4; ++r) zz[r] = fsigm(az[r]);
      // r gate
      f32x4 ar_;
      #pragma unroll
      for (int r = 0; r < 4; ++r) ar_[r] = s_uv[2 * 64 + e] * sv[r] + s_uv[3 * 64 + e];
      #pragma unroll
      for (int ks = 0; ks < 2; ++ks) {
        bf16x8 afr = ldfrag(&s_hbf[l * 72 + ks * 32 + quad * 8]);
        ar_ = mfma16(afr, ldfrag(&s_grT[e * 72 + ks * 32 + quad * 8]), ar_);
      }
      // h*r -> s_dfhr bf16
      #pragma unroll
      for (int r = 0; r < 4; ++r)
        s_dfhr[(quad * 4 + r) * 72 + e] = f2b(hreg[r] * fsigm(ar_[r]));
      __syncthreads();
      // candidate
      f32x4 ah;
      #pragma unroll
      for (int r = 0; r < 4; ++r) ah[r] = s_uv[4 * 64 + e] * sv[r] + s_uv[5 * 64 + e];
      #pragma unroll
      for (int ks = 0; ks < 2; ++ks) {
        bf16x8 afr = ldfrag(&s_dfhr[l * 72 + ks * 32 + quad * 8]);
        ah = mfma16(afr, ldfrag(&s_ghT[e * 72 + ks * 32 + quad * 8]), ah);
      }
      #pragma unroll
      for (int r = 0; r < 4; ++r) {
        float ht = ftanh(ah[r]);
        hreg[r] = zz[r] * hreg[r] + (1.f - zz[r]) * ht;
      }
      #pragma unroll
      for (int r = 0; r < 4; ++r)
        s_hbf[(quad * 4 + r) * 72 + e] = f2b(hreg[r]);
      if (t == T_ - 1) {
        #pragma unroll
        for (int r = 0; r < 4; ++r)
          hb[(r0 + quad * 4 + r) * 64 + e] = hreg[r];
      }
      __syncthreads();
    }
  }
}

// ================= classifier =================
__global__ void k_cls(Params p) {
  __shared__ float red[256][4];
  const int b = blockIdx.x, i = threadIdx.x;
  const float* hr = p.h + ((size_t)b * N_ + i) * 64;
  const float* w = p.clswf + (size_t)i * 64 * 4;
  float a0 = 0, a1 = 0, a2 = 0, a3 = 0;
  for (int f = 0; f < 64; ++f) {
    float hv = hr[f];
    a0 += hv * w[f * 4 + 0]; a1 += hv * w[f * 4 + 1];
    a2 += hv * w[f * 4 + 2]; a3 += hv * w[f * 4 + 3];
  }
  red[i][0] = a0; red[i][1] = a1; red[i][2] = a2; red[i][3] = a3;
  __syncthreads();
  for (int st = 128; st > 0; st >>= 1) {
    if (i < st) {
      red[i][0] += red[i + st][0]; red[i][1] += red[i + st][1];
      red[i][2] += red[i + st][2]; red[i][3] += red[i + st][3];
    }
    __syncthreads();
  }
  if (i < 4) {
    float v = red[0][i] + p.clsbf[i];
    if (*p.flag) ((float*)p.out)[b * 4 + i] = v;
    else         ((u16*)p.out)[b * 4 + i] = f2b(v);
  }
}

extern "C" void kernel_launch(void* const* d_in, const int* in_sizes, int n_in,
                              void* d_out, int out_size, void* d_ws, size_t ws_size,
                              hipStream_t stream) {
  float* w = (float*)d_ws;
  size_t o = 0;
  auto alloc = [&](size_t n) { float* r = w + o; o += (n + 63) & ~(size_t)63; return r; };
  float* xf    = alloc(262144);
  float* ewf   = alloc(E_);
  float* gwf   = alloc(FG_ * 64);
  float* gbf   = alloc(64);
  float* b1f   = alloc(64);
  float* b2ff  = alloc(64);
  float* wzcf  = alloc(64); float* bzcf = alloc(64); float* wzlf = alloc(8192); float* bzlf = alloc(64);
  float* wrcf  = alloc(64); float* brcf = alloc(64); float* wrlf = alloc(8192); float* brlf = alloc(64);
  float* whcf  = alloc(64); float* bhcf = alloc(64); float* whlf = alloc(8192); float* bhlf = alloc(64);
  float* clswf = alloc(65536); float* clsbf = alloc(64);
  u16* w1h = (u16*)alloc(2048);
  u16* w2h = (u16*)alloc(2048);
  int* flag = (int*)alloc(64);
  float* AnT   = alloc(65536);
  float* dinvS = alloc(256);
  float* uvF   = alloc(384);
  float* XW    = alloc((size_t)B_ * N_ * 64);
  float* de1   = alloc((size_t)B_ * N_ * 32);  // packed bf16 u32
  float* de2   = alloc((size_t)B_ * N_ * 32);
  const size_t zero_off = o;
  float* Ascr  = alloc((size_t)N_ * N_);
  float* h     = alloc((size_t)B_ * N_ * 64);
  float* Msum  = alloc((size_t)B_ * N_ * N_);
  float* degs  = alloc((size_t)B_ * N_);
  int*   bar   = (int*)alloc(B_ * 64);
  float* Eh    = alloc((size_t)B_ * S_ * N_ * N_);
  if (ws_size < o * sizeof(float)) return;

  (void)hipMemsetAsync(w + zero_off, 0, (o - zero_off) * sizeof(float), stream);

  Params p;
  p.x0  = d_in[0];  p.ew0 = d_in[1];
  p.gw0 = d_in[2];  p.gb0 = d_in[3];
  p.w10 = d_in[4];  p.b10 = d_in[5];
  p.w20 = d_in[6];  p.b20 = d_in[7];
  p.wzc0 = d_in[8];  p.bzc0 = d_in[9];  p.wzl0 = d_in[10]; p.bzl0 = d_in[11];
  p.wrc0 = d_in[12]; p.brc0 = d_in[13]; p.wrl0 = d_in[14]; p.brl0 = d_in[15];
  p.whc0 = d_in[16]; p.bhc0 = d_in[17]; p.whl0 = d_in[18]; p.bhl0 = d_in[19];
  p.clsw0 = d_in[20]; p.clsb0 = d_in[21];
  p.eidx = (const int*)d_in[22];
  p.xf = xf; p.ewf = ewf; p.gwf = gwf; p.gbf = gbf; p.b1f = b1f; p.b2ff = b2ff;
  p.wzcf = wzcf; p.bzcf = bzcf; p.wzlf = wzlf; p.bzlf = bzlf;
  p.wrcf = wrcf; p.brcf = brcf; p.wrlf = wrlf; p.brlf = brlf;
  p.whcf = whcf; p.bhcf = bhcf; p.whlf = whlf; p.bhlf = bhlf;
  p.clswf = clswf; p.clsbf = clsbf; p.w1h = w1h; p.w2h = w2h;
  p.AnT = AnT; p.dinvS = dinvS; p.uvF = uvF; p.XW = XW; p.de1 = de1; p.de2 = de2;
  p.h = h; p.Msum = Msum; p.degsum = degs; p.Eh = Eh; p.Ascr = Ascr;
  p.bar = bar; p.flag = flag; p.out = d_out;

  k_detect<<<1, 64, 0, stream>>>(p);
  k_convert<<<53, 256, 0, stream>>>(p);
  k_scatter<<<1, 256, 0, stream>>>(p);
  k_deg<<<1, 256, 0, stream>>>(p);
  k_ant<<<N_, 256, 0, stream>>>(p);
  k_uv<<<1, 64, 0, stream>>>(p);

  void* args[] = { &p };
  hipError_t ce = hipLaunchCooperativeKernel((const void*)dtgcn_main,
                                             dim3(B_ * G_), dim3(256), args, 0, stream);
  if (ce != hipSuccess) {
    (void)hipGetLastError();
    dtgcn_main<<<dim3(B_ * G_), dim3(256), 0, stream>>>(p);
  }

  k_cls<<<B_, 256, 0, stream>>>(p);
}